// Round 8
// baseline (161.028 us; speedup 1.0000x reference)
//
#include <hip/hip_runtime.h>
#include <math.h>

// CTC-CRF NLL: mean_b( logZ_den(b) - logZ_num(b) ), B=16,T=2048,S=8,L=256.
//
// R19 = R17's proven 2-step composition math (absmax 0) + R18's proven
// batch preloading. Cross-round law: a serial scan element costs ~180-220
// apparent cycles REGARDLESS of instruction count (R13->R15: 34->17 instr,
// -6%) or single-load exposure (R18 preload: -10%); only reducing the
// SERIAL ELEMENT COUNT pays proportionally (R16 den split). R17 halved
// element count (1023 steps -> 512 groups) but regressed because each
// group had 3 serially-exposed LDS reads (630cy/group). R19 de-exposes:
// fast chunks (16 t-steps = 8 double-groups) preload ALL stream float4s
// (fwd 24, bwd 32) + consumer ring values (8 float4 + 2 ints) up front,
// pin()-fenced; groups run pure-register. Chunk grid, ring [2][10][64]
// float4 layout, renorm-after-groups-3/7 schedule, generic R17 chunk for
// fwd chunk 0 (odd-aligned): unchanged. Ring indices re-audited (fwd
// consumer <- producer lane 63; bwd consumer <- producer lane 0).
// Den roles (R16 time-split) + staging + combine: verbatim.

#define LOG2E 1.4426950408889634f
#define LN2   0.69314718055994531f
#define CTL_WSHL1  0x130            // DPP wave_shl:1 (lane63 -> 0)
#define CTL_WSHR1  0x138            // DPP wave_shr:1 (lane0  -> 0)
#define CTL_ROR(r) (0x120 + (r))    // DPP row_ror:r

#define AST(p, v) __hip_atomic_store((p), (v), __ATOMIC_RELAXED, __HIP_MEMORY_SCOPE_AGENT)
#define ALD(p)    __hip_atomic_load((p), __ATOMIC_RELAXED, __HIP_MEMORY_SCOPE_AGENT)

template <int CTRL>
__device__ __forceinline__ float fdpp(float x) {
    return __int_as_float(__builtin_amdgcn_update_dpp(
        0, __float_as_int(x), CTRL, 0xF, 0xF, true));
}
template <int CTRL>
__device__ __forceinline__ int idpp(int x) {
    return __builtin_amdgcn_update_dpp(0, x, CTRL, 0xF, 0xF, true);
}

__device__ __forceinline__ void pin() {
#if __has_builtin(__builtin_amdgcn_sched_barrier)
    __builtin_amdgcn_sched_barrier(0);
#else
    asm volatile("" ::: "memory");
#endif
}

__device__ __forceinline__ float fexp2(float x) {
#if __has_builtin(__builtin_amdgcn_exp2f)
    return __builtin_amdgcn_exp2f(x);
#else
    return exp2f(x);
#endif
}
__device__ __forceinline__ float flog2(float x) {
#if __has_builtin(__builtin_amdgcn_logf)
    return __builtin_amdgcn_logf(x);
#else
    return __log2f(x);
#endif
}
__device__ __forceinline__ float lse2(float a, float b) {   // log2(2^a+2^b)
    float m = fmaxf(a, b);
    float d = fminf(a, b) - m;
    return m + flog2(1.0f + fexp2(d));
}

// ===================== numerator: constants (R17) =====================
struct FwdC {
    float kE0a,kE0b,kE0c,kE0d, kE1a,kE1b,kE1c,kE1d,
          kX0a,kX0b,kX0c,kX0d, kX1a,kX1b,kX1c,kX1d;
    float tee0,txe0,tee1,txe1,tex0,txx0,tex1,txx1;
};
struct BwdC {
    float kA,kB,kC,kD,kE,kF,kG,kH,kI,kJ,kK,kL,kM,kN,kO,kP;
    float tex0,txx0,tex1,txx1,teeN0,txeN0,teeN1,txeN1;
};

// ===================== forward: register-operand double group ============
template <bool CONS>
__device__ __forceinline__ void fw_double_reg(
    float4 a0, float4 a1, float4 ap, float4 rv,
    float& E0, float& E1, float& X0, float& X1,
    float fs0, const FwdC& c, float4* rb, int k, int lane)
{
    const float av = a0.x, cv = a0.y, a2 = a0.z, c2 = a0.w;
    const float bv = a1.x, dv = a1.y, b2 = a1.z, d2 = a1.w;
    const float bp = ap.x, dp = ap.y;
    const float a2bp = a2 * bp, a2dp = a2 * dp, b2a = b2 * av, b2c = b2 * cv,
                c2a = c2 * av, c2c = c2 * cv, d2b = d2 * bv, d2d = d2 * dv;
    const float cE0a = a2bp * c.kE0a, cE0b = a2bp * c.kE0b,
                cE0c = a2dp * c.kE0c, cE0d = a2dp * c.kE0d;
    const float cE1a = b2a * c.kE1a, cE1b = b2a * c.kE1b,
                cE1c = b2c * c.kE1c, cE1d = b2c * c.kE1d;
    const float cX0a = c2a * c.kX0a, cX0b = c2a * c.kX0b,
                cX0c = c2c * c.kX0c, cX0d = c2c * c.kX0d;
    const float cX1a = d2b * c.kX1a, cX1b = d2b * c.kX1b,
                cX1c = d2d * c.kX1c, cX1d = d2d * c.kX1d;
    float eh0 = fdpp<CTL_WSHR1>(E0), eh1 = fdpp<CTL_WSHR1>(E1);
    float xh0 = fdpp<CTL_WSHR1>(X0), xh1 = fdpp<CTL_WSHR1>(X1);
    if (CONS && lane == 0) { eh0 = rv.x; eh1 = rv.y; xh0 = rv.z; xh1 = rv.w; }
    eh0 *= fs0; eh1 *= fs0; xh0 *= fs0; xh1 *= fs0;
    const float nE0 = fmaf(cE0a, eh0, cE0b * xh0) + fmaf(cE0c, eh1, cE0d * xh1);
    const float nE1 = fmaf(cE1a, eh1, cE1b * xh1) + fmaf(cE1c, E0, cE1d * X0);
    const float nX0 = fmaf(cX0a, eh1, cX0b * xh1) + fmaf(cX0c, E0, cX0d * X0);
    const float nX1 = fmaf(cX1a, E0, cX1b * X0) + fmaf(cX1c, E1, cX1d * X1);
    E0 = nE0; E1 = nE1; X0 = nX0; X1 = nX1;
    if (!CONS) rb[(k + 1) * 64 + lane] = make_float4(E0, E1, X0, X1);
}

// LDS-operand wrappers (generic path, R17 verbatim)
template <bool CONS>
__device__ __forceinline__ void fw_single(
    const float2* f20, const float2* f21, int t,
    float& E0, float& E1, float& X0, float& X1,
    float fs0, const FwdC& c, float4* rb, int k, int lane)
{
    const float2 p0 = f20[t], p1 = f21[t];
    float4 rv = make_float4(0.f,0.f,0.f,0.f);
    if (CONS) rv = rb[k * 64 + 63];
    float nbE = fdpp<CTL_WSHR1>(E1);
    float nbX = fdpp<CTL_WSHR1>(X1);
    if (CONS && lane == 0) { nbE = rv.y; nbX = rv.w; }
    nbE *= fs0; nbX *= fs0;
    const float nE0 = p0.x * fmaf(nbE, c.tee0, nbX * c.txe0);
    const float nE1 = p1.x * fmaf(E0, c.tee1, X0 * c.txe1);
    const float nX0 = p0.y * fmaf(E0, c.tex0, X0 * c.txx0);
    const float nX1 = p1.y * fmaf(E1, c.tex1, X1 * c.txx1);
    E0 = nE0; E1 = nE1; X0 = nX0; X1 = nX1;
    if (!CONS) rb[(k + 1) * 64 + lane] = make_float4(E0, E1, X0, X1);
}

template <bool CONS>
__device__ __forceinline__ void fw_double(
    const float4* s40, const float4* s41, const float4* s4p, int th2,
    float& E0, float& E1, float& X0, float& X1,
    float fs0, const FwdC& c, float4* rb, int k, int lane)
{
    float4 rv = make_float4(0.f,0.f,0.f,0.f);
    if (CONS) rv = rb[k * 64 + 63];
    fw_double_reg<CONS>(s40[th2], s41[th2], s4p[th2], rv,
                        E0, E1, X0, X1, fs0, c, rb, k, lane);
}

template <bool CONS>
__device__ __forceinline__ void fw_renorm_pre(
    float& E0, float& E1, float& X0, float& X1, int& s, float& fs0,
    int rsv, int g, int lane, float4* rb, int k1, int* rs, int slot)
{
    float m = fmaxf(fmaxf(E0, E1), fmaxf(X0, X1));
    const bool live = (m > 0.0f);
    const int ex = live ? ((int)(__float_as_uint(m) >> 23) - 126) : 0;
    s += ex;
    int bs = idpp<CTL_WSHR1>(s);
    if (CONS && lane == 0) bs = rsv;
    if (!live) s = bs;
    int d = (g == 0) ? 0 : (bs - s);
    const int extra = (d > 30) ? d : 0;
    s += extra; d -= extra;
    const float fsc = ldexpf(1.0f, -(ex + extra));
    E0 *= fsc; E1 *= fsc; X0 *= fsc; X1 *= fsc;
    fs0 = (g == 0) ? 0.0f : ldexpf(1.0f, d);
    if (!CONS) {
        rs[slot * 64 + lane] = s;
        rb[k1 * 64 + lane] = make_float4(E0, E1, X0, X1);
    }
}

template <bool CONS>
__device__ __forceinline__ void fw_renorm(
    float& E0, float& E1, float& X0, float& X1, int& s, float& fs0,
    int g, int lane, float4* rb, int k1, int* rs, int slot)
{
    int rsv = 0;
    if (CONS) rsv = rs[slot * 64 + 63];
    fw_renorm_pre<CONS>(E0, E1, X0, X1, s, fs0, rsv, g, lane, rb, k1, rs, slot);
}

// generic chunk (R17 verbatim): lead single + doubles + tail single
template <bool CONS>
__device__ __forceinline__ void fw_chunk(
    const float2* f20, const float2* f21,
    const float4* s40, const float4* s41, const float4* s4p,
    float& E0, float& E1, float& X0, float& X1, int& s, float& fs0,
    const FwdC& c, int g, int lane, float4* rb, int* rs, int tb, int te)
{
    if (!CONS) rb[lane] = make_float4(E0, E1, X0, X1);   // carry slot 0
    int t = tb, gk = 0;
    if (t & 1) {
        fw_single<CONS>(f20, f21, t, E0, E1, X0, X1, fs0, c, rb, gk, lane);
        ++t; ++gk;
    }
    const int nd = (te >= t) ? ((te - t + 1) >> 1) : 0;
    const int th2 = t >> 1;
    for (int i = 0; i < nd; ++i) {
        fw_double<CONS>(s40, s41, s4p, th2 + i, E0, E1, X0, X1, fs0, c, rb, gk + i, lane);
        if (((gk + i) & 3) == 3)
            fw_renorm<CONS>(E0, E1, X0, X1, s, fs0, g, lane, rb, gk + i + 1, rs, (gk + i) >> 2);
    }
    t += 2 * nd; gk += nd;
    if (t <= te) {
        fw_single<CONS>(f20, f21, t, E0, E1, X0, X1, fs0, c, rb, gk, lane);
        if ((gk & 3) == 3)
            fw_renorm<CONS>(E0, E1, X0, X1, s, fs0, g, lane, rb, gk + 1, rs, gk >> 2);
    }
}

// fast chunk: tb even, 16 t-steps = 8 double groups, fully preloaded
template <bool CONS>
__device__ __forceinline__ void fw_chunk_fast(
    const float4* s40, const float4* s41, const float4* s4p, int tb,
    float& E0, float& E1, float& X0, float& X1, int& s, float& fs0,
    const FwdC& c, int g, int lane, float4* rb, int* rs)
{
    const int h = tb >> 1;
    if (!CONS) rb[lane] = make_float4(E0, E1, X0, X1);   // carry slot 0
    float4 RV[8]; int RS0 = 0, RS1 = 0;
    if (CONS) {
#pragma unroll
        for (int k = 0; k < 8; ++k) RV[k] = rb[k * 64 + 63];   // producer lane 63
        RS0 = rs[63]; RS1 = rs[64 + 63];
    } else {
#pragma unroll
        for (int k = 0; k < 8; ++k) RV[k] = make_float4(0.f,0.f,0.f,0.f);
    }
    float4 A0[4], A1[4], AP[4];
#pragma unroll
    for (int j = 0; j < 4; ++j) { A0[j]=s40[h+j]; A1[j]=s41[h+j]; AP[j]=s4p[h+j]; }
    pin();
    float4 B0[4], B1[4], BP[4];
#pragma unroll
    for (int j = 0; j < 4; ++j) { B0[j]=s40[h+4+j]; B1[j]=s41[h+4+j]; BP[j]=s4p[h+4+j]; }
    pin();
#pragma unroll
    for (int i = 0; i < 4; ++i)
        fw_double_reg<CONS>(A0[i], A1[i], AP[i], RV[i],
                            E0, E1, X0, X1, fs0, c, rb, i, lane);
    fw_renorm_pre<CONS>(E0, E1, X0, X1, s, fs0, RS0, g, lane, rb, 4, rs, 0);
#pragma unroll
    for (int i = 0; i < 4; ++i)
        fw_double_reg<CONS>(B0[i], B1[i], BP[i], RV[4 + i],
                            E0, E1, X0, X1, fs0, c, rb, 4 + i, lane);
    fw_renorm_pre<CONS>(E0, E1, X0, X1, s, fs0, RS1, g, lane, rb, 8, rs, 1);
}

// ===================== backward: register-operand double group ===========
template <bool CONS>
__device__ __forceinline__ void bw_double_reg(
    float4 a0, float4 a1, float4 an, float4 an2, float4 rv,
    float& bE0, float& bE1, float& bX0, float& bX1,
    float fs, const BwdC& c, float4* rb, int k, int lane)
{
    const float av = a0.z, cv = a0.w, a2 = a0.x, c2 = a0.y;
    const float bv = a1.z, dv = a1.w, b2 = a1.x, d2 = a1.y;
    const float au = an.z, cu = an.w, a2u = an.x;
    const float bu = an2.z;
    const float c2c = c2 * cv, c2b = c2 * bv, b2d = b2 * dv, b2au = b2 * au,
                d2d = d2 * dv, d2au = d2 * au, a2ucu = a2u * cu, a2ubu = a2u * bu;
    const float cE0x0 = c2c * c.kA, cE0e1 = c2b * c.kB,
                cE0x1 = b2d * c.kC, cE0e0u = b2au * c.kD;
    const float cX0x0 = c2c * c.kE, cX0e1 = c2b * c.kF,
                cX0x1 = b2d * c.kG, cX0e0u = b2au * c.kH;
    const float cE1x1 = d2d * c.kI, cE1e0u = d2au * c.kJ,
                cE1x0u = a2ucu * c.kK, cE1e1u = a2ubu * c.kL;
    const float cX1x1 = d2d * c.kM, cX1e0u = d2au * c.kN,
                cX1x0u = a2ucu * c.kO, cX1e1u = a2ubu * c.kP;
    float e0u = fdpp<CTL_WSHL1>(bE0);
    float x0u = fdpp<CTL_WSHL1>(bX0);
    float e1u = fdpp<CTL_WSHL1>(bE1);
    if (CONS && lane == 63) { e0u = rv.x; e1u = rv.y; x0u = rv.z; }
    e0u *= fs; x0u *= fs; e1u *= fs;
    const float nE0 = fmaf(cE0x0, bX0, cE0e1 * bE1) + fmaf(cE0x1, bX1, cE0e0u * e0u);
    const float nX0 = fmaf(cX0x0, bX0, cX0e1 * bE1) + fmaf(cX0x1, bX1, cX0e0u * e0u);
    const float nE1 = fmaf(cE1x1, bX1, cE1e0u * e0u) + fmaf(cE1x0u, x0u, cE1e1u * e1u);
    const float nX1 = fmaf(cX1x1, bX1, cX1e0u * e0u) + fmaf(cX1x0u, x0u, cX1e1u * e1u);
    bE0 = nE0; bE1 = nE1; bX0 = nX0; bX1 = nX1;
    if (!CONS) rb[(k + 1) * 64 + lane] = make_float4(bE0, bE1, bX0, bX1);
}

template <bool CONS>
__device__ __forceinline__ void bw_single(
    const float2* f20, const float2* f21, const float2* f2n, int t,
    float& bE0, float& bE1, float& bX0, float& bX1,
    float fs, const BwdC& c, float4* rb, int k, int lane)
{
    const float2 p0 = f20[t], p1 = f21[t], pn = f2n[t];
    float4 rv = make_float4(0.f,0.f,0.f,0.f);
    if (CONS) rv = rb[k * 64];           // producer lane 0
    const float mm0 = p0.x * bE0;
    float mup = fdpp<CTL_WSHL1>(mm0);
    if (CONS && lane == 63) mup = pn.x * rv.x;
    mup *= fs;
    const float m10 = p0.y * bX0, m11 = p1.y * bX1, mm1 = p1.x * bE1;
    const float nE0 = fmaf(c.tex0, m10, c.teeN0 * mm1);
    const float nX0 = fmaf(c.txx0, m10, c.txeN0 * mm1);
    const float nE1 = fmaf(c.tex1, m11, c.teeN1 * mup);
    const float nX1 = fmaf(c.txx1, m11, c.txeN1 * mup);
    bE0 = nE0; bE1 = nE1; bX0 = nX0; bX1 = nX1;
    if (!CONS) rb[(k + 1) * 64 + lane] = make_float4(bE0, bE1, bX0, bX1);
}

template <bool CONS>
__device__ __forceinline__ void bw_double(
    const float4* s40, const float4* s41, const float4* s4n, const float4* s4n2,
    int th2, float& bE0, float& bE1, float& bX0, float& bX1,
    float fs, const BwdC& c, float4* rb, int k, int lane)
{
    float4 rv = make_float4(0.f,0.f,0.f,0.f);
    if (CONS) rv = rb[k * 64];           // producer lane 0
    bw_double_reg<CONS>(s40[th2], s41[th2], s4n[th2], s4n2[th2], rv,
                        bE0, bE1, bX0, bX1, fs, c, rb, k, lane);
}

template <bool CONS>
__device__ __forceinline__ void bw_renorm_pre(
    float& bE0, float& bE1, float& bX0, float& bX1, int& s, float& fs,
    int rsv, int g, int lane, float4* rb, int k1, int* rs, int slot)
{
    float m = fmaxf(fmaxf(bE0, bE1), fmaxf(bX0, bX1));
    const bool live = (m > 0.0f);
    const int ex = live ? ((int)(__float_as_uint(m) >> 23) - 126) : 0;
    s += ex;
    int bs = idpp<CTL_WSHL1>(s);
    if (CONS && lane == 63) bs = rsv;
    if (!live) s = bs;
    int d = (g == 127) ? 0 : (bs - s);
    const int extra = (d > 30) ? d : 0;
    s += extra; d -= extra;
    const float fsc = ldexpf(1.0f, -(ex + extra));
    bE0 *= fsc; bE1 *= fsc; bX0 *= fsc; bX1 *= fsc;
    fs = (g == 127) ? 0.0f : ldexpf(1.0f, d);
    if (!CONS) {
        rs[slot * 64 + lane] = s;
        rb[k1 * 64 + lane] = make_float4(bE0, bE1, bX0, bX1);
    }
}

template <bool CONS>
__device__ __forceinline__ void bw_renorm(
    float& bE0, float& bE1, float& bX0, float& bX1, int& s, float& fs,
    int g, int lane, float4* rb, int k1, int* rs, int slot)
{
    int rsv = 0;
    if (CONS) rsv = rs[slot * 64];       // producer lane 0
    bw_renorm_pre<CONS>(bE0, bE1, bX0, bX1, s, fs, rsv, g, lane, rb, k1, rs, slot);
}

// generic chunk (R17 verbatim)
template <bool CONS>
__device__ __forceinline__ void bw_chunk(
    const float2* f20, const float2* f21, const float2* f2n,
    const float4* s40, const float4* s41, const float4* s4n, const float4* s4n2,
    float& bE0, float& bE1, float& bX0, float& bX1, int& s, float& fs,
    const BwdC& c, int g, int lane, float4* rb, int* rs, int tbh, int tbl)
{
    if (!CONS) rb[lane] = make_float4(bE0, bE1, bX0, bX1);   // carry slot 0
    int t = tbh, gk = 0;
    if (!(t & 1)) {
        bw_single<CONS>(f20, f21, f2n, t, bE0, bE1, bX0, bX1, fs, c, rb, gk, lane);
        --t; ++gk;
    }
    const int nd = (t >= tbl) ? ((t - tbl + 1) >> 1) : 0;
    const int th2 = t >> 1;
    for (int i = 0; i < nd; ++i) {
        bw_double<CONS>(s40, s41, s4n, s4n2, th2 - i, bE0, bE1, bX0, bX1, fs, c, rb, gk + i, lane);
        if (((gk + i) & 3) == 3)
            bw_renorm<CONS>(bE0, bE1, bX0, bX1, s, fs, g, lane, rb, gk + i + 1, rs, (gk + i) >> 2);
    }
    t -= 2 * nd; gk += nd;
    if (t >= tbl) {
        bw_single<CONS>(f20, f21, f2n, t, bE0, bE1, bX0, bX1, fs, c, rb, gk, lane);
        if ((gk & 3) == 3)
            bw_renorm<CONS>(bE0, bE1, bX0, bX1, s, fs, g, lane, rb, gk + 1, rs, gk >> 2);
    }
}

// fast chunk: tbh odd, 16 t-steps = 8 double groups, fully preloaded
template <bool CONS>
__device__ __forceinline__ void bw_chunk_fast(
    const float4* s40, const float4* s41, const float4* s4n, const float4* s4n2,
    int tbh, float& bE0, float& bE1, float& bX0, float& bX1, int& s, float& fs,
    const BwdC& c, int g, int lane, float4* rb, int* rs)
{
    const int th2 = tbh >> 1;
    if (!CONS) rb[lane] = make_float4(bE0, bE1, bX0, bX1);   // carry slot 0
    float4 RV[8]; int RS0 = 0, RS1 = 0;
    if (CONS) {
#pragma unroll
        for (int k = 0; k < 8; ++k) RV[k] = rb[k * 64];      // producer lane 0
        RS0 = rs[0]; RS1 = rs[64];                           // producer lane 0
    } else {
#pragma unroll
        for (int k = 0; k < 8; ++k) RV[k] = make_float4(0.f,0.f,0.f,0.f);
    }
    float4 A0[4], A1[4], AN[4], AN2[4];
#pragma unroll
    for (int j = 0; j < 4; ++j) {
        A0[j] = s40[th2 - j]; A1[j] = s41[th2 - j];
        AN[j] = s4n[th2 - j]; AN2[j] = s4n2[th2 - j];
    }
    pin();
    float4 B0[4], B1[4], BN[4], BN2[4];
#pragma unroll
    for (int j = 0; j < 4; ++j) {
        B0[j] = s40[th2 - 4 - j]; B1[j] = s41[th2 - 4 - j];
        BN[j] = s4n[th2 - 4 - j]; BN2[j] = s4n2[th2 - 4 - j];
    }
    pin();
#pragma unroll
    for (int i = 0; i < 4; ++i)
        bw_double_reg<CONS>(A0[i], A1[i], AN[i], AN2[i], RV[i],
                            bE0, bE1, bX0, bX1, fs, c, rb, i, lane);
    bw_renorm_pre<CONS>(bE0, bE1, bX0, bX1, s, fs, RS0, g, lane, rb, 4, rs, 0);
#pragma unroll
    for (int i = 0; i < 4; ++i)
        bw_double_reg<CONS>(B0[i], B1[i], BN[i], BN2[i], RV[4 + i],
                            bE0, bE1, bX0, bX1, fs, c, rb, 4 + i, lane);
    bw_renorm_pre<CONS>(bE0, bE1, bX0, bX1, s, fs, RS1, g, lane, rb, 8, rs, 1);
}

// ---------------- denominator steps (proven) ----------------
__device__ __forceinline__ float denf_step(float al, float emt, const float* Tr) {
    float v1 = fdpp<CTL_ROR(1)>(al);
    float v2 = fdpp<CTL_ROR(2)>(al);
    float v3 = fdpp<CTL_ROR(3)>(al);
    float v4 = fdpp<CTL_ROR(4)>(al);
    float v5 = fdpp<CTL_ROR(5)>(al);
    float v6 = fdpp<CTL_ROR(6)>(al);
    float v7 = fdpp<CTL_ROR(7)>(al);
    float q0 = fmaf(v1, Tr[1], al * Tr[0]);
    float q1 = fmaf(v3, Tr[3], v2 * Tr[2]);
    float q2 = fmaf(v5, Tr[5], v4 * Tr[4]);
    float q3 = fmaf(v7, Tr[7], v6 * Tr[6]);
    return ((q0 + q1) + (q2 + q3)) * emt;
}
__device__ __forceinline__ float denb_step(float al, float emt, const float* TrB) {
    float g  = al * emt;
    float v1 = fdpp<CTL_ROR(7)>(g);
    float v2 = fdpp<CTL_ROR(6)>(g);
    float v3 = fdpp<CTL_ROR(5)>(g);
    float v4 = fdpp<CTL_ROR(4)>(g);
    float v5 = fdpp<CTL_ROR(3)>(g);
    float v6 = fdpp<CTL_ROR(2)>(g);
    float v7 = fdpp<CTL_ROR(1)>(g);
    float q0 = fmaf(v1, TrB[1], g * TrB[0]);
    float q1 = fmaf(v3, TrB[3], v2 * TrB[2]);
    float q2 = fmaf(v5, TrB[5], v4 * TrB[4]);
    float q3 = fmaf(v7, TrB[7], v6 * TrB[6]);
    return (q0 + q1) + (q2 + q3);
}
__device__ __forceinline__ int den_renorm(float& al) {
    float mm = fmaxf(al, fdpp<CTL_ROR(4)>(al));
    mm = fmaxf(mm, fdpp<CTL_ROR(2)>(mm));
    mm = fmaxf(mm, fdpp<CTL_ROR(1)>(mm));
    const int ex = (int)(__float_as_uint(mm) >> 23) - 126;
    al = ldexpf(al, -ex);
    return ex;
}

#define WXP(i, j) fexp2(trans[(i) * S + (j)] * LOG2E)

extern "C" __global__ void __launch_bounds__(128)
crf_fused(const float* __restrict__ em, const float* __restrict__ trans,
          const float* __restrict__ bos, const float* __restrict__ eos,
          const int* __restrict__ lengths, const int* __restrict__ targets,
          const int* __restrict__ tlens,
          float* __restrict__ ws, float* __restrict__ out,
          int B, int T, int S, int L)
{
    extern __shared__ float sm[];
    const int bid  = blockIdx.x;
    const int tid  = threadIdx.x;
    const int lane = tid & 63;
    const int wv   = tid >> 6;
    const int half = S >> 1;                 // = 4
    const int role = bid / B;                // 0 nf, 1 nb, 2 den-real, 3 matF, 4 matB
    const int b    = bid % B;
    const float* gem = em + (size_t)b * T * S;
    const int len = lengths[b];
    const int tm  = (len - 1) >> 1;
    const int P2  = T + 2;                   // padded float2 pitch per stream
    const int RINGF = 8 * P2;                // ring offset (floats)

    float* NF  = ws + 16 + (size_t)b * 640;
    float* NB  = ws + 16 + (size_t)B * 640 + (size_t)b * 640;
    const size_t DENR = 16 + (size_t)(2 * B) * 640;
    const size_t MATF = DENR + (size_t)B * 32;
    const size_t MATB = MATF + (size_t)B * 128;
    int* ticket = (int*)ws;

    // segment boundaries for den split (R16)
    const int tq  = tm >> 1;
    const int dlo = tm + 1, dhi = len - 1;
    const int tq2 = (dhi >= dlo) ? (dlo + ((dhi - dlo) >> 1)) : (dlo - 1);

    // ---------------- staging ----------------
    if (role < 2) {
        float2* s2 = (float2*)sm;
        for (int t = tid; t < T; t += 128) {
            const float4* gr = (const float4*)(gem + t * S);
            float4 a = gr[0], c4 = gr[1];
            s2[0 * P2 + t] = make_float2(fexp2(a.x * LOG2E), fexp2(c4.x * LOG2E));
            s2[1 * P2 + t] = make_float2(fexp2(a.y * LOG2E), fexp2(c4.y * LOG2E));
            s2[2 * P2 + t] = make_float2(fexp2(a.z * LOG2E), fexp2(c4.z * LOG2E));
            s2[3 * P2 + t] = make_float2(fexp2(a.w * LOG2E), fexp2(c4.w * LOG2E));
        }
    } else {
        for (int t = tid; t < T; t += 128) {
            const float4* gr = (const float4*)(gem + t * S);
            float4 a = gr[0], c4 = gr[1];
            float4 w0, w1;
            w0.x = fexp2(a.x * LOG2E); w0.y = fexp2(c4.x * LOG2E);
            w0.z = fexp2(a.y * LOG2E); w0.w = fexp2(c4.y * LOG2E);
            w1.x = fexp2(a.z * LOG2E); w1.y = fexp2(c4.z * LOG2E);
            w1.z = fexp2(a.w * LOG2E); w1.w = fexp2(c4.w * LOG2E);
            ((float4*)sm)[t * 2]     = w0;
            ((float4*)sm)[t * 2 + 1] = w1;
        }
    }
    __syncthreads();

    float4* ring4  = (float4*)(sm + RINGF);          // [2][10][64] float4
    int*    ringSB = (int*)(sm + RINGF + 5120);      // [2][2][64] int

    if (role == 0) {
        // ===== NUM FWD, double-step 2-wave pipeline (preloaded): t=1..tm =====
        const float2* s2v = (const float2*)sm;
        const int g   = (wv << 6) + lane;
        const int u0 = g * 2;
        const int base = b * L;
        const int e0 = targets[base + ((u0     < L) ? u0     : (L - 1))];
        const int e1 = targets[base + ((u0 + 1 < L) ? u0 + 1 : (L - 1))];
        const int ep  = (u0 > 0) ? targets[base + u0 - 1] : e0;
        const int e0p = (u0 > 1) ? targets[base + u0 - 2] : e0;
        FwdC c;
        c.tee0 = WXP(ep, e0);          c.txe0 = WXP(ep + half, e0);
        c.tee1 = WXP(e0, e1);          c.txe1 = WXP(e0 + half, e1);
        c.tex0 = WXP(e0, e0 + half);   c.txx0 = WXP(e0 + half, e0 + half);
        c.tex1 = WXP(e1, e1 + half);   c.txx1 = WXP(e1 + half, e1 + half);
        const float tee1p = WXP(e0p, ep);        const float txe1p = WXP(e0p + half, ep);
        const float tex1p = WXP(ep, ep + half);  const float txx1p = WXP(ep + half, ep + half);
        c.kE0a = c.tee0 * tee1p; c.kE0b = c.tee0 * txe1p;
        c.kE0c = c.txe0 * tex1p; c.kE0d = c.txe0 * txx1p;
        c.kE1a = c.tee1 * c.tee0; c.kE1b = c.tee1 * c.txe0;
        c.kE1c = c.txe1 * c.tex0; c.kE1d = c.txe1 * c.txx0;
        c.kX0a = c.tex0 * c.tee0; c.kX0b = c.tex0 * c.txe0;
        c.kX0c = c.txx0 * c.tex0; c.kX0d = c.txx0 * c.txx0;
        c.kX1a = c.tex1 * c.tee1; c.kX1b = c.tex1 * c.txe1;
        c.kX1c = c.txx1 * c.tex1; c.kX1d = c.txx1 * c.txx1;
        const float2* f20 = s2v + e0 * P2;
        const float2* f21 = s2v + e1 * P2;
        const float4* s40 = (const float4*)f20;
        const float4* s41 = (const float4*)f21;
        const float4* s4p = (const float4*)(s2v + ep * P2);
        float E0 = 0.f, E1 = 0.f, X0 = 0.f, X1 = 0.f;
        int s = 0;
        if (g == 0) E0 = fexp2(bos[e0] * LOG2E) * f20[0].x;
        float fs0 = (g == 0) ? 0.0f : 1.0f;

        const int NCH = (tm >= 1) ? ((tm >> 4) + 1) : 0;
        for (int ph = 0; ph <= NCH; ++ph) {
            const int ci = (wv == 0) ? ph : ph - 1;   // producer = wave0
            if (ci >= 0 && ci < NCH) {
                const int tb = ci ? (ci << 4) : 1;
                int te = (ci << 4) + 15; if (te > tm) te = tm;
                float4* rb = ring4 + (ci & 1) * (10 * 64);
                int*    rs = ringSB + (ci & 1) * 128;
                if (ci && te == (ci << 4) + 15) {
                    if (wv == 0)
                        fw_chunk_fast<false>(s40, s41, s4p, tb,
                                             E0, E1, X0, X1, s, fs0, c, g, lane, rb, rs);
                    else
                        fw_chunk_fast<true>(s40, s41, s4p, tb,
                                            E0, E1, X0, X1, s, fs0, c, g, lane, rb, rs);
                } else {
                    if (wv == 0)
                        fw_chunk<false>(f20, f21, s40, s41, s4p,
                                        E0, E1, X0, X1, s, fs0, c, g, lane, rb, rs, tb, te);
                    else
                        fw_chunk<true>(f20, f21, s40, s41, s4p,
                                       E0, E1, X0, X1, s, fs0, c, g, lane, rb, rs, tb, te);
                }
            }
            __syncthreads();
        }
        AST(&NF[g * 4 + 0], E0);
        AST(&NF[g * 4 + 1], E1);
        AST(&NF[g * 4 + 2], X0);
        AST(&NF[g * 4 + 3], X1);
        AST(&NF[512 + g], __int_as_float(s));
    } else if (role == 1) {
        // ===== NUM BWD, double-step 2-wave pipeline (preloaded) =====
        const float2* s2v = (const float2*)sm;
        const int g   = (wv << 6) + lane;
        const int u0 = g * 2;
        const int base = b * L;
        const int e0 = targets[base + ((u0     < L) ? u0     : (L - 1))];
        const int e1 = targets[base + ((u0 + 1 < L) ? u0 + 1 : (L - 1))];
        const int e2 = targets[base + ((u0 + 2 < L) ? u0 + 2 : (L - 1))];
        const int e3 = targets[base + ((u0 + 3 < L) ? u0 + 3 : (L - 1))];
        BwdC c;
        c.tex0 = WXP(e0, e0 + half);  c.txx0 = WXP(e0 + half, e0 + half);
        c.tex1 = WXP(e1, e1 + half);  c.txx1 = WXP(e1 + half, e1 + half);
        c.teeN0 = WXP(e0, e1);        c.txeN0 = WXP(e0 + half, e1);
        c.teeN1 = WXP(e1, e2);        c.txeN1 = WXP(e1 + half, e2);
        const float tex0n = WXP(e2, e2 + half);
        const float teeN0n = WXP(e2, e3);
        c.kA = c.tex0 * c.txx0;  c.kB = c.tex0 * c.txeN0;
        c.kC = c.teeN0 * c.tex1; c.kD = c.teeN0 * c.teeN1;
        c.kE = c.txx0 * c.txx0;  c.kF = c.txx0 * c.txeN0;
        c.kG = c.txeN0 * c.tex1; c.kH = c.txeN0 * c.teeN1;
        c.kI = c.tex1 * c.txx1;  c.kJ = c.tex1 * c.txeN1;
        c.kK = c.teeN1 * tex0n;  c.kL = c.teeN1 * teeN0n;
        c.kM = c.txx1 * c.txx1;  c.kN = c.txx1 * c.txeN1;
        c.kO = c.txeN1 * tex0n;  c.kP = c.txeN1 * teeN0n;
        const float2* f20 = s2v + e0 * P2;
        const float2* f21 = s2v + e1 * P2;
        const float2* f2n = s2v + e2 * P2;
        const float4* s40 = (const float4*)f20;
        const float4* s41 = (const float4*)f21;
        const float4* s4n = (const float4*)f2n;
        const float4* s4n2 = (const float4*)(s2v + e3 * P2);
        float bE0 = 0.f, bE1 = 0.f, bX0 = 0.f, bX1 = 0.f;
        const int uf = tlens[b] - 1;
        if (g == (uf >> 1)) {
            const int kf = uf & 1;
            const int ef = kf ? e1 : e0;
            if (kf) { bE1 = fexp2(eos[ef] * LOG2E); bX1 = fexp2(eos[ef + half] * LOG2E); }
            else    { bE0 = fexp2(eos[ef] * LOG2E); bX0 = fexp2(eos[ef + half] * LOG2E); }
        }
        int s = 0;
        float fs = (g == 127) ? 0.0f : 1.0f;

        const int th = len - 1, tlo = tm + 1;
        const int nbs = th - tlo + 1;
        const int NCH = (nbs > 0) ? ((nbs + 15) >> 4) : 0;
        for (int ph = 0; ph <= NCH; ++ph) {
            const int ci = (wv == 1) ? ph : ph - 1;   // producer = wave1
            if (ci >= 0 && ci < NCH) {
                const int tbh = th - (ci << 4);
                int tbl = tbh - 15; if (tbl < tlo) tbl = tlo;
                float4* rb = ring4 + (ci & 1) * (10 * 64);
                int*    rs = ringSB + (ci & 1) * 128;
                if ((tbh - tbl == 15) && (tbh & 1)) {
                    if (wv == 1)
                        bw_chunk_fast<false>(s40, s41, s4n, s4n2, tbh,
                                             bE0, bE1, bX0, bX1, s, fs, c, g, lane, rb, rs);
                    else
                        bw_chunk_fast<true>(s40, s41, s4n, s4n2, tbh,
                                            bE0, bE1, bX0, bX1, s, fs, c, g, lane, rb, rs);
                } else {
                    if (wv == 1)
                        bw_chunk<false>(f20, f21, f2n, s40, s41, s4n, s4n2,
                                        bE0, bE1, bX0, bX1, s, fs, c, g, lane, rb, rs, tbh, tbl);
                    else
                        bw_chunk<true>(f20, f21, f2n, s40, s41, s4n, s4n2,
                                       bE0, bE1, bX0, bX1, s, fs, c, g, lane, rb, rs, tbh, tbl);
                }
            }
            __syncthreads();
        }
        AST(&NB[g * 4 + 0], bE0);
        AST(&NB[g * 4 + 1], bE1);
        AST(&NB[g * 4 + 2], bX0);
        AST(&NB[g * 4 + 3], bX1);
        AST(&NB[512 + g], __int_as_float(s));
    } else if (role == 2) {
        // =================== DEN REAL (R16, proven) ===================
        float* DR = ws + DENR + (size_t)b * 32;
        const int j  = lane & 7;
        const int jj = ((j & 3) << 1) + (j >> 2);
        if (wv == 0) {
            float Tr[8];
#pragma unroll
            for (int r = 0; r < 8; ++r)
                Tr[r] = fexp2(trans[((j - r) & 7) * S + j] * LOG2E);
            float al = fexp2(bos[j] * LOG2E) * sm[jj];
            int sc = 0;
            int t = 1;
            if (t + 3 <= tq) {
                float c0 = sm[t * 8 + jj];
                float c1 = sm[(t + 1) * 8 + jj];
                float c2 = sm[(t + 2) * 8 + jj];
                float c3 = sm[(t + 3) * 8 + jj];
                pin();
                while (t + 7 <= tq) {
                    float d0 = sm[(t + 4) * 8 + jj];
                    float d1 = sm[(t + 5) * 8 + jj];
                    float d2 = sm[(t + 6) * 8 + jj];
                    float d3 = sm[(t + 7) * 8 + jj];
                    pin();
                    al = denf_step(al, c0, Tr);
                    al = denf_step(al, c1, Tr);
                    al = denf_step(al, c2, Tr);
                    al = denf_step(al, c3, Tr);
                    sc += den_renorm(al);
                    c0 = d0; c1 = d1; c2 = d2; c3 = d3;
                    t += 4;
                }
                al = denf_step(al, c0, Tr);
                al = denf_step(al, c1, Tr);
                al = denf_step(al, c2, Tr);
                al = denf_step(al, c3, Tr);
                sc += den_renorm(al);
                t += 4;
            }
            while (t <= tq) { al = denf_step(al, sm[t * 8 + jj], Tr); ++t; }
            if (lane < 8) {
                AST(&DR[j], al);
                if (j == 0) AST(&DR[8], __int_as_float(sc));
            }
        } else {
            float TrB[8];
#pragma unroll
            for (int r = 0; r < 8; ++r)
                TrB[r] = fexp2(trans[j * S + ((j + r) & 7)] * LOG2E);
            float al = fexp2(eos[j] * LOG2E);
            int sc = 0;
            int t = dhi;
            const int tloR = tq2 + 1;
            if (t - 3 >= tloR) {
                float c0 = sm[t * 8 + jj];
                float c1 = sm[(t - 1) * 8 + jj];
                float c2 = sm[(t - 2) * 8 + jj];
                float c3 = sm[(t - 3) * 8 + jj];
                pin();
                while (t - 7 >= tloR) {
                    float d0 = sm[(t - 4) * 8 + jj];
                    float d1 = sm[(t - 5) * 8 + jj];
                    float d2 = sm[(t - 6) * 8 + jj];
                    float d3 = sm[(t - 7) * 8 + jj];
                    pin();
                    al = denb_step(al, c0, TrB);
                    al = denb_step(al, c1, TrB);
                    al = denb_step(al, c2, TrB);
                    al = denb_step(al, c3, TrB);
                    sc += den_renorm(al);
                    c0 = d0; c1 = d1; c2 = d2; c3 = d3;
                    t -= 4;
                }
                al = denb_step(al, c0, TrB);
                al = denb_step(al, c1, TrB);
                al = denb_step(al, c2, TrB);
                al = denb_step(al, c3, TrB);
                sc += den_renorm(al);
                t -= 4;
            }
            while (t >= tloR) { al = denb_step(al, sm[t * 8 + jj], TrB); --t; }
            if (lane < 8) {
                AST(&DR[16 + j], al);
                if (j == 0) AST(&DR[24], __int_as_float(sc));
            }
        }
    } else if (role == 3) {
        // =================== DEN MATRIX FWD (R16, proven) ===================
        float* MF = ws + MATF + (size_t)b * 128;
        const int j  = lane & 7;
        const int jj = ((j & 3) << 1) + (j >> 2);
        const int cc = (wv << 2) + (lane >> 4);
        float Tr[8];
#pragma unroll
        for (int r = 0; r < 8; ++r)
            Tr[r] = fexp2(trans[((j - r) & 7) * S + j] * LOG2E);
        float al = (j == cc) ? 1.0f : 0.0f;
        int sc = 0;
        int t = tq + 1;
        if (t + 3 <= tm) {
            float c0 = sm[t * 8 + jj];
            float c1 = sm[(t + 1) * 8 + jj];
            float c2 = sm[(t + 2) * 8 + jj];
            float c3 = sm[(t + 3) * 8 + jj];
            pin();
            while (t + 7 <= tm) {
                float d0 = sm[(t + 4) * 8 + jj];
                float d1 = sm[(t + 5) * 8 + jj];
                float d2 = sm[(t + 6) * 8 + jj];
                float d3 = sm[(t + 7) * 8 + jj];
                pin();
                al = denf_step(al, c0, Tr);
                al = denf_step(al, c1, Tr);
                al = denf_step(al, c2, Tr);
                al = denf_step(al, c3, Tr);
                sc += den_renorm(al);
                c0 = d0; c1 = d1; c2 = d2; c3 = d3;
                t += 4;
            }
            al = denf_step(al, c0, Tr);
            al = denf_step(al, c1, Tr);
            al = denf_step(al, c2, Tr);
            al = denf_step(al, c3, Tr);
            sc += den_renorm(al);
            t += 4;
        }
        while (t <= tm) { al = denf_step(al, sm[t * 8 + jj], Tr); ++t; }
        if ((lane & 15) < 8) {
            AST(&MF[cc * 8 + j], al);
            if (j == 0) AST(&MF[64 + cc], __int_as_float(sc));
        }
    } else {
        // =================== DEN MATRIX BWD (R16, proven) ===================
        float* MB = ws + MATB + (size_t)b * 128;
        const int j  = lane & 7;
        const int jj = ((j & 3) << 1) + (j >> 2);
        const int cc = (wv << 2) + (lane >> 4);
        float TrB[8];
#pragma unroll
        for (int r = 0; r < 8; ++r)
            TrB[r] = fexp2(trans[j * S + ((j + r) & 7)] * LOG2E);
        float al = (j == cc) ? 1.0f : 0.0f;
        int sc = 0;
        int t = tq2;
        if (t - 3 >= dlo) {
            float c0 = sm[t * 8 + jj];
            float c1 = sm[(t - 1) * 8 + jj];
            float c2 = sm[(t - 2) * 8 + jj];
            float c3 = sm[(t - 3) * 8 + jj];
            pin();
            while (t - 7 >= dlo) {
                float d0 = sm[(t - 4) * 8 + jj];
                float d1 = sm[(t - 5) * 8 + jj];
                float d2 = sm[(t - 6) * 8 + jj];
                float d3 = sm[(t - 7) * 8 + jj];
                pin();
                al = denb_step(al, c0, TrB);
                al = denb_step(al, c1, TrB);
                al = denb_step(al, c2, TrB);
                al = denb_step(al, c3, TrB);
                sc += den_renorm(al);
                c0 = d0; c1 = d1; c2 = d2; c3 = d3;
                t -= 4;
            }
            al = denb_step(al, c0, TrB);
            al = denb_step(al, c1, TrB);
            al = denb_step(al, c2, TrB);
            al = denb_step(al, c3, TrB);
            sc += den_renorm(al);
            t -= 4;
        }
        while (t >= dlo) { al = denb_step(al, sm[t * 8 + jj], TrB); --t; }
        if ((lane & 15) < 8) {
            AST(&MB[cc * 8 + j], al);
            if (j == 0) AST(&MB[64 + cc], __int_as_float(sc));
        }
    }

    // ---------------- ticket + winner combine (R16, proven) ----------------
    __syncthreads();
    int* wflag = (int*)sm;
    if (tid == 0) {
        __threadfence();
        const int tk = atomicAdd(ticket, 1);
        wflag[0] = (tk == 5 * B - 1) ? 1 : 0;
    }
    __syncthreads();
    if (wflag[0] && tid < 64) {
        __threadfence();
        float acc = 0.0f;
        const int c8 = lane >> 3, j8 = lane & 7;
        for (int bb2 = 0; bb2 < B; ++bb2) {
            const float* nf = ws + 16 + (size_t)bb2 * 640;
            const float* nb = ws + 16 + (size_t)B * 640 + (size_t)bb2 * 640;
            float va = 0.0f, vb = 0.0f;
#pragma unroll
            for (int k = 0; k < 4; ++k)
                va = fmaf(ALD(&nf[lane * 4 + k]), ALD(&nb[lane * 4 + k]), va);
#pragma unroll
            for (int k = 0; k < 4; ++k)
                vb = fmaf(ALD(&nf[256 + lane * 4 + k]),
                          ALD(&nb[256 + lane * 4 + k]), vb);
            const int sa = __float_as_int(ALD(&nf[512 + lane]))
                         + __float_as_int(ALD(&nb[512 + lane]));
            const int sb = __float_as_int(ALD(&nf[576 + lane]))
                         + __float_as_int(ALD(&nb[576 + lane]));
            float pa = (va > 0.0f) ? (flog2(va) + (float)sa) : -3.0e38f;
            float pb = (vb > 0.0f) ? (flog2(vb) + (float)sb) : -3.0e38f;
            float part = lse2(pa, pb);
#pragma unroll
            for (int o = 1; o < 64; o <<= 1)
                part = lse2(part, __shfl_xor(part, o, 64));

            const float* dr = ws + DENR + (size_t)bb2 * 32;
            const float* mf = ws + MATF + (size_t)bb2 * 128;
            const float* mb = ws + MATB + (size_t)bb2 * 128;
            int s1 = __float_as_int(ALD(&mf[64 + c8]));
            int m1 = s1;
#pragma unroll
            for (int o = 8; o < 64; o <<= 1) {
                int oth = __shfl_xor(m1, o, 64);
                m1 = (oth > m1) ? oth : m1;
            }
            int s2 = __float_as_int(ALD(&mb[64 + c8]));
            int m2 = s2;
#pragma unroll
            for (int o = 8; o < 64; o <<= 1) {
                int oth = __shfl_xor(m2, o, 64);
                m2 = (oth > m2) ? oth : m2;
            }
            float t1 = ALD(&dr[c8]) * ALD(&mf[c8 * 8 + j8])
                     * ldexpf(1.0f, s1 - m1);
#pragma unroll
            for (int o = 8; o < 64; o <<= 1) t1 += __shfl_xor(t1, o, 64);
            float t2 = ALD(&dr[16 + c8]) * ALD(&mb[c8 * 8 + j8])
                     * ldexpf(1.0f, s2 - m2);
#pragma unroll
            for (int o = 8; o < 64; o <<= 1) t2 += __shfl_xor(t2, o, 64);
            float pd = t1 * t2;
#pragma unroll
            for (int o = 1; o < 8; o <<= 1) pd += __shfl_xor(pd, o, 64);
            const int scF = __float_as_int(ALD(&dr[8]));
            const int scB = __float_as_int(ALD(&dr[24]));
            float logden = flog2(fmaxf(pd, 1e-37f))
                         + (float)(scF + scB + m1 + m2);
            if (lane == 0) acc += logden - part;
        }
        if (lane == 0) out[0] = acc * (LN2 / (float)B);
    }
}

extern "C" void kernel_launch(void* const* d_in, const int* in_sizes, int n_in,
                              void* d_out, int out_size, void* d_ws, size_t ws_size,
                              hipStream_t stream)
{
    const float* em      = (const float*)d_in[0];
    const float* trans   = (const float*)d_in[1];
    const float* bos     = (const float*)d_in[2];
    const float* eos     = (const float*)d_in[3];
    const int*   lengths = (const int*)d_in[4];
    const int*   targets = (const int*)d_in[5];
    const int*   tlens   = (const int*)d_in[6];
    float* out = (float*)d_out;
    float* ws  = (float*)d_ws;

    const int B  = in_sizes[4];              // 16
    const int SS = in_sizes[1];              // 64
    int S = 1; while (S * S < SS) ++S;       // 8
    const int T = in_sizes[0] / (B * S);     // 2048
    const int L = in_sizes[5] / B;           // 256

    // num blocks: streams 8*(T+2) + ring float4[2][10][64] (5120 floats)
    // + ringS int[2][2][64] (256). den blocks: T*8 + small. Request max.
    const size_t shmem = (size_t)(8 * (T + 2) + 5120 + 256) * sizeof(float);

    static bool attr_done = false;
    if (!attr_done) {
        (void)hipFuncSetAttribute((const void*)crf_fused,
                                  hipFuncAttributeMaxDynamicSharedMemorySize,
                                  (int)(96 * 1024));
        attr_done = true;
    }

    (void)hipMemsetAsync(ws, 0, 64, stream); // ticket
    hipLaunchKernelGGL(crf_fused, dim3(5 * B), dim3(128), shmem, stream,
                       em, trans, bos, eos, lengths, targets, tlens,
                       ws, out, B, T, S, L);
}

// Round 9
// 143.142 us; speedup vs baseline: 1.1250x; 1.1250x over previous
//
#include <hip/hip_runtime.h>
#include <math.h>

// CTC-CRF NLL: mean_b( logZ_den(b) - logZ_num(b) ), B=16,T=2048,S=8,L=256.
//
// R20 = R18 (best: 80.3us dispatch, absmax 0) + paired-chunk phases.
// Issue-bound law (R13..R19): adding instructions per serial element always
// loses (R17/R19 composition regressed); removing exposure wins (R18).
// R18 residual: ~2500cy per 16-step chunk vs ~1750cy of issue slots =>
// ~700cy/phase of barrier+imbalance overhead across 65 phases (~20us).
// R20 halves phase count: each phase runs TWO 16-step chunks (32 t-steps)
// before the barrier. Chunk internals (nf_/nb_chunk16, slow paths, renorm
// cadence, ring slot semantics) are BYTE-IDENTICAL R18 code; only:
//  - phase loop gains inner sub in {0,1}; ring gets 4 buffers
//    [mega-parity][sub]; ringSB offset moves (8704).
//  - LDS 102.5KB (cap 112KB; >=128KB proven in-harness at R12).
// Producer writes mega m at phase m; consumer reads at m+1; buffer reuse
// at m+2 is barrier-separated. Bitwise-identical math -> absmax 0.
// Den roles (R16 time-split) + staging + combine: verbatim.

#define LOG2E 1.4426950408889634f
#define LN2   0.69314718055994531f
#define CTL_WSHL1  0x130            // DPP wave_shl:1 (lane63 -> 0)
#define CTL_WSHR1  0x138            // DPP wave_shr:1 (lane0  -> 0)
#define CTL_ROR(r) (0x120 + (r))    // DPP row_ror:r

#define AST(p, v) __hip_atomic_store((p), (v), __ATOMIC_RELAXED, __HIP_MEMORY_SCOPE_AGENT)
#define ALD(p)    __hip_atomic_load((p), __ATOMIC_RELAXED, __HIP_MEMORY_SCOPE_AGENT)

template <int CTRL>
__device__ __forceinline__ float fdpp(float x) {
    return __int_as_float(__builtin_amdgcn_update_dpp(
        0, __float_as_int(x), CTRL, 0xF, 0xF, true));
}
template <int CTRL>
__device__ __forceinline__ int idpp(int x) {
    return __builtin_amdgcn_update_dpp(0, x, CTRL, 0xF, 0xF, true);
}

__device__ __forceinline__ void pin() {
#if __has_builtin(__builtin_amdgcn_sched_barrier)
    __builtin_amdgcn_sched_barrier(0);
#else
    asm volatile("" ::: "memory");
#endif
}

__device__ __forceinline__ float fexp2(float x) {
#if __has_builtin(__builtin_amdgcn_exp2f)
    return __builtin_amdgcn_exp2f(x);
#else
    return exp2f(x);
#endif
}
__device__ __forceinline__ float flog2(float x) {
#if __has_builtin(__builtin_amdgcn_logf)
    return __builtin_amdgcn_logf(x);
#else
    return __log2f(x);
#endif
}
__device__ __forceinline__ float lse2(float a, float b) {   // log2(2^a+2^b)
    float m = fmaxf(a, b);
    float d = fminf(a, b) - m;
    return m + flog2(1.0f + fexp2(d));
}

struct NFC { float tee0, txe0, tee1, txe1, tex0, txx0, tex1, txx1; };
struct NBC { float tex0, txx0, tex1, txx1, teeN0, txeN0, teeN1, txeN1; };

// ================= num fwd: one step (R15/R18 math, verbatim) =============
template <bool CONS>
__device__ __forceinline__ void nf_step(
    float2 p0, float2 p1, float2 rv, int k,
    float (&E)[2], float (&X)[2], float teeF, float txeF,
    const NFC& c, float2* rEX, int lane)
{
    float nbE = fdpp<CTL_WSHR1>(E[1]);
    float nbX = fdpp<CTL_WSHR1>(X[1]);
    if (CONS && lane == 0) { nbE = rv.x; nbX = rv.y; }
    const float nE0 = p0.x * fmaf(nbE, teeF, nbX * txeF);
    const float nE1 = p1.x * fmaf(E[0], c.tee1, X[0] * c.txe1);
    const float nX0 = p0.y * fmaf(E[0], c.tex0, X[0] * c.txx0);
    const float nX1 = p1.y * fmaf(E[1], c.tex1, X[1] * c.txx1);
    E[0] = nE0; E[1] = nE1; X[0] = nX0; X[1] = nX1;
    if (!CONS) rEX[(k + 1) * 64 + lane] = make_float2(E[1], X[1]);
}

template <bool CONS>
__device__ __forceinline__ void nf_renorm(
    float (&E)[2], float (&X)[2], int& s, float& teeF, float& txeF,
    int rsv, int g, int lane, const NFC& c,
    float2* rEX, int* rS, int k, int slot)
{
    float m = fmaxf(fmaxf(E[0], E[1]), fmaxf(X[0], X[1]));
    const bool live = (m > 0.0f);
    const int ex = live ? ((int)(__float_as_uint(m) >> 23) - 126) : 0;
    s += ex;
    int bs = idpp<CTL_WSHR1>(s);
    if (CONS && lane == 0) bs = rsv;
    if (!live) s = bs;
    int d = (g == 0) ? 0 : (bs - s);
    const int extra = (d > 30) ? d : 0;
    s += extra; d -= extra;
    const float fsc = ldexpf(1.0f, -(ex + extra));
    E[0] *= fsc; E[1] *= fsc; X[0] *= fsc; X[1] *= fsc;
    const float fs0 = (g == 0) ? 0.0f : ldexpf(1.0f, d);
    teeF = c.tee0 * fs0; txeF = c.txe0 * fs0;
    if (!CONS) {
        rS[slot * 64 + lane] = s;
        rEX[(k + 1) * 64 + lane] = make_float2(E[1], X[1]);
    }
}

// fast chunk: 16 steps, tb even. Ring + stream data batch-preloaded.
template <bool CONS>
__device__ __forceinline__ void nf_chunk16(
    const float4* s40, const float4* s41, int tb,
    float (&E)[2], float (&X)[2], int& s, float& teeF, float& txeF,
    const NFC& c, int g, int lane, float2* rEX, int* rS)
{
    const int h = tb >> 1;
    float2 RV[16]; int RS0 = 0, RS1 = 0;
    if (CONS) {
#pragma unroll
        for (int k = 0; k < 16; ++k) RV[k] = rEX[k * 64 + 63];
        RS0 = rS[63]; RS1 = rS[64 + 63];
    } else {
        rEX[lane] = make_float2(E[1], X[1]);     // carry-in slot 0
#pragma unroll
        for (int k = 0; k < 16; ++k) RV[k] = make_float2(0.f, 0.f);
    }
    float4 A0[4], A1[4];
#pragma unroll
    for (int j = 0; j < 4; ++j) { A0[j] = s40[h + j]; A1[j] = s41[h + j]; }
    pin();
    float4 B0[4], B1[4];
#pragma unroll
    for (int j = 0; j < 4; ++j) { B0[j] = s40[h + 4 + j]; B1[j] = s41[h + 4 + j]; }
    pin();
#pragma unroll
    for (int k = 0; k < 8; ++k) {
        const float4 v0 = A0[k >> 1], v1 = A1[k >> 1];
        const float2 p0 = (k & 1) ? make_float2(v0.z, v0.w) : make_float2(v0.x, v0.y);
        const float2 p1 = (k & 1) ? make_float2(v1.z, v1.w) : make_float2(v1.x, v1.y);
        nf_step<CONS>(p0, p1, RV[k], k, E, X, teeF, txeF, c, rEX, lane);
    }
    nf_renorm<CONS>(E, X, s, teeF, txeF, RS0, g, lane, c, rEX, rS, 7, 0);
#pragma unroll
    for (int k = 8; k < 16; ++k) {
        const float4 v0 = B0[(k - 8) >> 1], v1 = B1[(k - 8) >> 1];
        const float2 p0 = (k & 1) ? make_float2(v0.z, v0.w) : make_float2(v0.x, v0.y);
        const float2 p1 = (k & 1) ? make_float2(v1.z, v1.w) : make_float2(v1.x, v1.y);
        nf_step<CONS>(p0, p1, RV[k], k, E, X, teeF, txeF, c, rEX, lane);
    }
    nf_renorm<CONS>(E, X, s, teeF, txeF, RS1, g, lane, c, rEX, rS, 15, 1);
}

// slow chunk: arbitrary n, per-step loads (rare: fwd chunk 0 + tails)
template <bool CONS>
__device__ __forceinline__ void nf_chunk_slow(
    const float2* f20, const float2* f21, int tb, int n,
    float (&E)[2], float (&X)[2], int& s, float& teeF, float& txeF,
    const NFC& c, int g, int lane, float2* rEX, int* rS)
{
    if (!CONS) rEX[lane] = make_float2(E[1], X[1]);
    for (int k = 0; k < n; ++k) {
        const float2 p0 = f20[tb + k], p1 = f21[tb + k];
        float2 rv = make_float2(0.f, 0.f);
        if (CONS) rv = rEX[k * 64 + 63];
        nf_step<CONS>(p0, p1, rv, k, E, X, teeF, txeF, c, rEX, lane);
        if ((k & 7) == 7) {
            int rsv = 0;
            if (CONS) rsv = rS[(k >> 3) * 64 + 63];
            nf_renorm<CONS>(E, X, s, teeF, txeF, rsv, g, lane, c, rEX, rS, k, k >> 3);
        }
    }
}

// ================= num bwd: one step (R15/R18 math, verbatim) =============
template <bool CONS>
__device__ __forceinline__ void nb_step(
    float2 p0, float2 p1, float rm, int k,
    float (&bE)[2], float (&bX)[2], float teeN1F, float txeN1F,
    const NBC& c, float* rM, int lane)
{
    const float mm0 = p0.x * bE[0];
    const float mm1 = p1.x * bE[1];
    const float m10 = p0.y * bX[0];
    const float m11 = p1.y * bX[1];
    float mup = fdpp<CTL_WSHL1>(mm0);
    if (CONS && lane == 63) mup = rm;
    if (!CONS) rM[k * 64 + lane] = mm0;
    const float nE0 = fmaf(c.tex0, m10, c.teeN0 * mm1);
    const float nX0 = fmaf(c.txx0, m10, c.txeN0 * mm1);
    const float nE1 = fmaf(c.tex1, m11, teeN1F * mup);
    const float nX1 = fmaf(c.txx1, m11, txeN1F * mup);
    bE[0] = nE0; bE[1] = nE1; bX[0] = nX0; bX[1] = nX1;
}

template <bool CONS>
__device__ __forceinline__ void nb_renorm(
    float (&bE)[2], float (&bX)[2], int& s, float& teeN1F, float& txeN1F,
    int rsv, int g, int lane, const NBC& c, int* rS, int slot)
{
    float m = fmaxf(fmaxf(bE[0], bE[1]), fmaxf(bX[0], bX[1]));
    const bool live = (m > 0.0f);
    const int ex = live ? ((int)(__float_as_uint(m) >> 23) - 126) : 0;
    s += ex;
    int bs = idpp<CTL_WSHL1>(s);
    if (CONS && lane == 63) bs = rsv;
    if (!live) s = bs;
    int d = (g == 127) ? 0 : (bs - s);
    const int extra = (d > 30) ? d : 0;
    s += extra; d -= extra;
    const float fsc = ldexpf(1.0f, -(ex + extra));
    bE[0] *= fsc; bE[1] *= fsc; bX[0] *= fsc; bX[1] *= fsc;
    const float fs = (g == 127) ? 0.0f : ldexpf(1.0f, d);
    teeN1F = c.teeN1 * fs; txeN1F = c.txeN1 * fs;
    if (!CONS) rS[slot * 64 + lane] = s;
}

// fast chunk: 16 steps descending from tbh (odd)
template <bool CONS>
__device__ __forceinline__ void nb_chunk16(
    const float4* s40, const float4* s41, int tbh,
    float (&bE)[2], float (&bX)[2], int& s, float& teeN1F, float& txeN1F,
    const NBC& c, int g, int lane, float* rM, int* rS)
{
    const int h = tbh >> 1;
    float RM[16]; int RS0 = 0, RS1 = 0;
    if (CONS) {
#pragma unroll
        for (int k = 0; k < 16; ++k) RM[k] = rM[k * 64];     // producer lane 0
        RS0 = rS[0]; RS1 = rS[64];                           // producer lane 0
    } else {
#pragma unroll
        for (int k = 0; k < 16; ++k) RM[k] = 0.f;
    }
    float4 A0[4], A1[4];
#pragma unroll
    for (int j = 0; j < 4; ++j) { A0[j] = s40[h - j]; A1[j] = s41[h - j]; }
    pin();
    float4 B0[4], B1[4];
#pragma unroll
    for (int j = 0; j < 4; ++j) { B0[j] = s40[h - 4 - j]; B1[j] = s41[h - 4 - j]; }
    pin();
#pragma unroll
    for (int k = 0; k < 8; ++k) {
        const float4 v0 = A0[k >> 1], v1 = A1[k >> 1];
        // t = tbh - k; k even -> t odd -> high half (z,w)
        const float2 p0 = (k & 1) ? make_float2(v0.x, v0.y) : make_float2(v0.z, v0.w);
        const float2 p1 = (k & 1) ? make_float2(v1.x, v1.y) : make_float2(v1.z, v1.w);
        nb_step<CONS>(p0, p1, RM[k], k, bE, bX, teeN1F, txeN1F, c, rM, lane);
    }
    nb_renorm<CONS>(bE, bX, s, teeN1F, txeN1F, RS0, g, lane, c, rS, 0);
#pragma unroll
    for (int k = 8; k < 16; ++k) {
        const float4 v0 = B0[(k - 8) >> 1], v1 = B1[(k - 8) >> 1];
        const float2 p0 = (k & 1) ? make_float2(v0.x, v0.y) : make_float2(v0.z, v0.w);
        const float2 p1 = (k & 1) ? make_float2(v1.x, v1.y) : make_float2(v1.z, v1.w);
        nb_step<CONS>(p0, p1, RM[k], k, bE, bX, teeN1F, txeN1F, c, rM, lane);
    }
    nb_renorm<CONS>(bE, bX, s, teeN1F, txeN1F, RS1, g, lane, c, rS, 1);
}

template <bool CONS>
__device__ __forceinline__ void nb_chunk_slow(
    const float2* f20, const float2* f21, int tbh, int n,
    float (&bE)[2], float (&bX)[2], int& s, float& teeN1F, float& txeN1F,
    const NBC& c, int g, int lane, float* rM, int* rS)
{
    for (int k = 0; k < n; ++k) {
        const float2 p0 = f20[tbh - k], p1 = f21[tbh - k];
        float rm = 0.f;
        if (CONS) rm = rM[k * 64];
        nb_step<CONS>(p0, p1, rm, k, bE, bX, teeN1F, txeN1F, c, rM, lane);
        if ((k & 7) == 7) {
            int rsv = 0;
            if (CONS) rsv = rS[(k >> 3) * 64];
            nb_renorm<CONS>(bE, bX, s, teeN1F, txeN1F, rsv, g, lane, c, rS, k >> 3);
        }
    }
}

// ---------------- denominator steps (proven) ----------------
__device__ __forceinline__ float denf_step(float al, float emt, const float* Tr) {
    float v1 = fdpp<CTL_ROR(1)>(al);
    float v2 = fdpp<CTL_ROR(2)>(al);
    float v3 = fdpp<CTL_ROR(3)>(al);
    float v4 = fdpp<CTL_ROR(4)>(al);
    float v5 = fdpp<CTL_ROR(5)>(al);
    float v6 = fdpp<CTL_ROR(6)>(al);
    float v7 = fdpp<CTL_ROR(7)>(al);
    float q0 = fmaf(v1, Tr[1], al * Tr[0]);
    float q1 = fmaf(v3, Tr[3], v2 * Tr[2]);
    float q2 = fmaf(v5, Tr[5], v4 * Tr[4]);
    float q3 = fmaf(v7, Tr[7], v6 * Tr[6]);
    return ((q0 + q1) + (q2 + q3)) * emt;
}
__device__ __forceinline__ float denb_step(float al, float emt, const float* TrB) {
    float g  = al * emt;
    float v1 = fdpp<CTL_ROR(7)>(g);
    float v2 = fdpp<CTL_ROR(6)>(g);
    float v3 = fdpp<CTL_ROR(5)>(g);
    float v4 = fdpp<CTL_ROR(4)>(g);
    float v5 = fdpp<CTL_ROR(3)>(g);
    float v6 = fdpp<CTL_ROR(2)>(g);
    float v7 = fdpp<CTL_ROR(1)>(g);
    float q0 = fmaf(v1, TrB[1], g * TrB[0]);
    float q1 = fmaf(v3, TrB[3], v2 * TrB[2]);
    float q2 = fmaf(v5, TrB[5], v4 * TrB[4]);
    float q3 = fmaf(v7, TrB[7], v6 * TrB[6]);
    return (q0 + q1) + (q2 + q3);
}
__device__ __forceinline__ int den_renorm(float& al) {
    float mm = fmaxf(al, fdpp<CTL_ROR(4)>(al));
    mm = fmaxf(mm, fdpp<CTL_ROR(2)>(mm));
    mm = fmaxf(mm, fdpp<CTL_ROR(1)>(mm));
    const int ex = (int)(__float_as_uint(mm) >> 23) - 126;
    al = ldexpf(al, -ex);
    return ex;
}

#define WXP(i, j) fexp2(trans[(i) * S + (j)] * LOG2E)

extern "C" __global__ void __launch_bounds__(128)
crf_fused(const float* __restrict__ em, const float* __restrict__ trans,
          const float* __restrict__ bos, const float* __restrict__ eos,
          const int* __restrict__ lengths, const int* __restrict__ targets,
          const int* __restrict__ tlens,
          float* __restrict__ ws, float* __restrict__ out,
          int B, int T, int S, int L)
{
    extern __shared__ float sm[];
    const int bid  = blockIdx.x;
    const int tid  = threadIdx.x;
    const int lane = tid & 63;
    const int wv   = tid >> 6;
    const int half = S >> 1;                 // = 4
    const int role = bid / B;                // 0 nf, 1 nb, 2 den-real, 3 matF, 4 matB
    const int b    = bid % B;
    const float* gem = em + (size_t)b * T * S;
    const int len = lengths[b];
    const int tm  = (len - 1) >> 1;
    const int P2  = T + 2;                   // padded float2 pitch per stream
    const int RINGF = 8 * P2;                // ring offset (floats)

    float* NF  = ws + 16 + (size_t)b * 640;
    float* NB  = ws + 16 + (size_t)B * 640 + (size_t)b * 640;
    const size_t DENR = 16 + (size_t)(2 * B) * 640;
    const size_t MATF = DENR + (size_t)B * 32;
    const size_t MATB = MATF + (size_t)B * 128;
    int* ticket = (int*)ws;

    // segment boundaries for den split (R16)
    const int tq  = tm >> 1;
    const int dlo = tm + 1, dhi = len - 1;
    const int tq2 = (dhi >= dlo) ? (dlo + ((dhi - dlo) >> 1)) : (dlo - 1);

    // ---------------- staging ----------------
    if (role < 2) {
        float2* s2 = (float2*)sm;
        for (int t = tid; t < T; t += 128) {
            const float4* gr = (const float4*)(gem + t * S);
            float4 a = gr[0], c4 = gr[1];
            s2[0 * P2 + t] = make_float2(fexp2(a.x * LOG2E), fexp2(c4.x * LOG2E));
            s2[1 * P2 + t] = make_float2(fexp2(a.y * LOG2E), fexp2(c4.y * LOG2E));
            s2[2 * P2 + t] = make_float2(fexp2(a.z * LOG2E), fexp2(c4.z * LOG2E));
            s2[3 * P2 + t] = make_float2(fexp2(a.w * LOG2E), fexp2(c4.w * LOG2E));
        }
    } else {
        for (int t = tid; t < T; t += 128) {
            const float4* gr = (const float4*)(gem + t * S);
            float4 a = gr[0], c4 = gr[1];
            float4 w0, w1;
            w0.x = fexp2(a.x * LOG2E); w0.y = fexp2(c4.x * LOG2E);
            w0.z = fexp2(a.y * LOG2E); w0.w = fexp2(c4.y * LOG2E);
            w1.x = fexp2(a.z * LOG2E); w1.y = fexp2(c4.z * LOG2E);
            w1.z = fexp2(a.w * LOG2E); w1.w = fexp2(c4.w * LOG2E);
            ((float4*)sm)[t * 2]     = w0;
            ((float4*)sm)[t * 2 + 1] = w1;
        }
    }
    __syncthreads();

    // 4 ring buffers: [mega-parity][sub]
    float2* ringEX = (float2*)(sm + RINGF);       // 4 x [17][64] float2 (fwd)
    float*  ringM  = sm + RINGF;                  // 4 x [16][64] float  (bwd)
    int*    ringSB = (int*)(sm + RINGF + 8704);   // 4 x [2][64] int

    if (role == 0) {
        // ===== NUM FWD, preloaded 2-wave pipeline, 2 chunks/phase =====
        const float2* s2v = (const float2*)sm;
        const int g   = (wv << 6) + lane;
        const int u0 = g * 2;
        const int base = b * L;
        const int e0 = targets[base + ((u0     < L) ? u0     : (L - 1))];
        const int e1 = targets[base + ((u0 + 1 < L) ? u0 + 1 : (L - 1))];
        const int ep = (u0 > 0) ? targets[base + u0 - 1] : e0;
        NFC c;
        c.tee0 = WXP(ep, e0);          c.txe0 = WXP(ep + half, e0);
        c.tee1 = WXP(e0, e1);          c.txe1 = WXP(e0 + half, e1);
        c.tex0 = WXP(e0, e0 + half);   c.txx0 = WXP(e0 + half, e0 + half);
        c.tex1 = WXP(e1, e1 + half);   c.txx1 = WXP(e1 + half, e1 + half);
        const float2* f20 = s2v + e0 * P2;
        const float2* f21 = s2v + e1 * P2;
        const float4* s40 = (const float4*)f20;
        const float4* s41 = (const float4*)f21;
        float E[2] = {0.f, 0.f}, X[2] = {0.f, 0.f};
        int s = 0;
        if (g == 0) E[0] = fexp2(bos[e0] * LOG2E) * f20[0].x;
        float teeF = (g == 0) ? 0.0f : c.tee0;
        float txeF = (g == 0) ? 0.0f : c.txe0;

        const int NCH = (tm >= 1) ? ((tm >> 4) + 1) : 0;
        const int NMG = (NCH + 1) >> 1;
        for (int ph = 0; ph <= NMG; ++ph) {
            const int mg = (wv == 0) ? ph : ph - 1;   // producer = wave0
            if (mg >= 0 && mg < NMG) {
                for (int sub = 0; sub < 2; ++sub) {
                    const int ci = 2 * mg + sub;
                    if (ci < NCH) {
                        const int tb = ci ? (ci << 4) : 1;
                        int te = (ci << 4) + 15; if (te > tm) te = tm;
                        const int bi = ((mg & 1) << 1) + sub;
                        float2* rEX = ringEX + bi * (17 * 64);
                        int*    rS  = ringSB + bi * 128;
                        if (ci && te == (ci << 4) + 15) {
                            if (wv == 0)
                                nf_chunk16<false>(s40, s41, tb, E, X, s, teeF, txeF,
                                                  c, g, lane, rEX, rS);
                            else
                                nf_chunk16<true>(s40, s41, tb, E, X, s, teeF, txeF,
                                                 c, g, lane, rEX, rS);
                        } else {
                            const int n = te - tb + 1;
                            if (wv == 0)
                                nf_chunk_slow<false>(f20, f21, tb, n, E, X, s, teeF, txeF,
                                                     c, g, lane, rEX, rS);
                            else
                                nf_chunk_slow<true>(f20, f21, tb, n, E, X, s, teeF, txeF,
                                                    c, g, lane, rEX, rS);
                        }
                    }
                }
            }
            __syncthreads();
        }
        AST(&NF[g * 4 + 0], E[0]);
        AST(&NF[g * 4 + 1], E[1]);
        AST(&NF[g * 4 + 2], X[0]);
        AST(&NF[g * 4 + 3], X[1]);
        AST(&NF[512 + g], __int_as_float(s));
    } else if (role == 1) {
        // ===== NUM BWD, preloaded 2-wave pipeline, 2 chunks/phase =====
        const float2* s2v = (const float2*)sm;
        const int g   = (wv << 6) + lane;
        const int u0 = g * 2;
        const int base = b * L;
        const int e0 = targets[base + ((u0     < L) ? u0     : (L - 1))];
        const int e1 = targets[base + ((u0 + 1 < L) ? u0 + 1 : (L - 1))];
        const int e2 = targets[base + ((u0 + 2 < L) ? u0 + 2 : (L - 1))];
        NBC c;
        c.tex0 = WXP(e0, e0 + half);  c.txx0 = WXP(e0 + half, e0 + half);
        c.tex1 = WXP(e1, e1 + half);  c.txx1 = WXP(e1 + half, e1 + half);
        c.teeN0 = WXP(e0, e1);        c.txeN0 = WXP(e0 + half, e1);
        c.teeN1 = WXP(e1, e2);        c.txeN1 = WXP(e1 + half, e2);
        if (g == 127) { c.teeN1 = 0.0f; c.txeN1 = 0.0f; }
        const float2* f20 = s2v + e0 * P2;
        const float2* f21 = s2v + e1 * P2;
        const float4* s40 = (const float4*)f20;
        const float4* s41 = (const float4*)f21;
        float bE[2] = {0.f, 0.f}, bX[2] = {0.f, 0.f};
        const int uf = tlens[b] - 1;
        if (g == (uf >> 1)) {
            const int kf = uf & 1;
            const int ef = kf ? e1 : e0;
            bE[kf] = fexp2(eos[ef] * LOG2E);
            bX[kf] = fexp2(eos[ef + half] * LOG2E);
        }
        int s = 0;
        float teeN1F = c.teeN1, txeN1F = c.txeN1;

        const int th = len - 1, tlo = tm + 1;
        const int nbs = th - tlo + 1;
        const int NCH = (nbs > 0) ? ((nbs + 15) >> 4) : 0;
        const int NMG = (NCH + 1) >> 1;
        for (int ph = 0; ph <= NMG; ++ph) {
            const int mg = (wv == 1) ? ph : ph - 1;   // producer = wave1
            if (mg >= 0 && mg < NMG) {
                for (int sub = 0; sub < 2; ++sub) {
                    const int ci = 2 * mg + sub;
                    if (ci < NCH) {
                        const int tbh = th - (ci << 4);
                        int tbl = tbh - 15; if (tbl < tlo) tbl = tlo;
                        const int n = tbh - tbl + 1;
                        const int bi = ((mg & 1) << 1) + sub;
                        float* rM = ringM + bi * 1024;
                        int*   rS = ringSB + bi * 128;
                        if (n == 16 && (tbh & 1)) {
                            if (wv == 1)
                                nb_chunk16<false>(s40, s41, tbh, bE, bX, s, teeN1F, txeN1F,
                                                  c, g, lane, rM, rS);
                            else
                                nb_chunk16<true>(s40, s41, tbh, bE, bX, s, teeN1F, txeN1F,
                                                 c, g, lane, rM, rS);
                        } else {
                            if (wv == 1)
                                nb_chunk_slow<false>(f20, f21, tbh, n, bE, bX, s, teeN1F, txeN1F,
                                                     c, g, lane, rM, rS);
                            else
                                nb_chunk_slow<true>(f20, f21, tbh, n, bE, bX, s, teeN1F, txeN1F,
                                                    c, g, lane, rM, rS);
                        }
                    }
                }
            }
            __syncthreads();
        }
        AST(&NB[g * 4 + 0], bE[0]);
        AST(&NB[g * 4 + 1], bE[1]);
        AST(&NB[g * 4 + 2], bX[0]);
        AST(&NB[g * 4 + 3], bX[1]);
        AST(&NB[512 + g], __int_as_float(s));
    } else if (role == 2) {
        // =================== DEN REAL (R16, proven) ===================
        float* DR = ws + DENR + (size_t)b * 32;
        const int j  = lane & 7;
        const int jj = ((j & 3) << 1) + (j >> 2);
        if (wv == 0) {
            float Tr[8];
#pragma unroll
            for (int r = 0; r < 8; ++r)
                Tr[r] = fexp2(trans[((j - r) & 7) * S + j] * LOG2E);
            float al = fexp2(bos[j] * LOG2E) * sm[jj];
            int sc = 0;
            int t = 1;
            if (t + 3 <= tq) {
                float c0 = sm[t * 8 + jj];
                float c1 = sm[(t + 1) * 8 + jj];
                float c2 = sm[(t + 2) * 8 + jj];
                float c3 = sm[(t + 3) * 8 + jj];
                pin();
                while (t + 7 <= tq) {
                    float d0 = sm[(t + 4) * 8 + jj];
                    float d1 = sm[(t + 5) * 8 + jj];
                    float d2 = sm[(t + 6) * 8 + jj];
                    float d3 = sm[(t + 7) * 8 + jj];
                    pin();
                    al = denf_step(al, c0, Tr);
                    al = denf_step(al, c1, Tr);
                    al = denf_step(al, c2, Tr);
                    al = denf_step(al, c3, Tr);
                    sc += den_renorm(al);
                    c0 = d0; c1 = d1; c2 = d2; c3 = d3;
                    t += 4;
                }
                al = denf_step(al, c0, Tr);
                al = denf_step(al, c1, Tr);
                al = denf_step(al, c2, Tr);
                al = denf_step(al, c3, Tr);
                sc += den_renorm(al);
                t += 4;
            }
            while (t <= tq) { al = denf_step(al, sm[t * 8 + jj], Tr); ++t; }
            if (lane < 8) {
                AST(&DR[j], al);
                if (j == 0) AST(&DR[8], __int_as_float(sc));
            }
        } else {
            float TrB[8];
#pragma unroll
            for (int r = 0; r < 8; ++r)
                TrB[r] = fexp2(trans[j * S + ((j + r) & 7)] * LOG2E);
            float al = fexp2(eos[j] * LOG2E);
            int sc = 0;
            int t = dhi;
            const int tloR = tq2 + 1;
            if (t - 3 >= tloR) {
                float c0 = sm[t * 8 + jj];
                float c1 = sm[(t - 1) * 8 + jj];
                float c2 = sm[(t - 2) * 8 + jj];
                float c3 = sm[(t - 3) * 8 + jj];
                pin();
                while (t - 7 >= tloR) {
                    float d0 = sm[(t - 4) * 8 + jj];
                    float d1 = sm[(t - 5) * 8 + jj];
                    float d2 = sm[(t - 6) * 8 + jj];
                    float d3 = sm[(t - 7) * 8 + jj];
                    pin();
                    al = denb_step(al, c0, TrB);
                    al = denb_step(al, c1, TrB);
                    al = denb_step(al, c2, TrB);
                    al = denb_step(al, c3, TrB);
                    sc += den_renorm(al);
                    c0 = d0; c1 = d1; c2 = d2; c3 = d3;
                    t -= 4;
                }
                al = denb_step(al, c0, TrB);
                al = denb_step(al, c1, TrB);
                al = denb_step(al, c2, TrB);
                al = denb_step(al, c3, TrB);
                sc += den_renorm(al);
                t -= 4;
            }
            while (t >= tloR) { al = denb_step(al, sm[t * 8 + jj], TrB); --t; }
            if (lane < 8) {
                AST(&DR[16 + j], al);
                if (j == 0) AST(&DR[24], __int_as_float(sc));
            }
        }
    } else if (role == 3) {
        // =================== DEN MATRIX FWD (R16, proven) ===================
        float* MF = ws + MATF + (size_t)b * 128;
        const int j  = lane & 7;
        const int jj = ((j & 3) << 1) + (j >> 2);
        const int cc = (wv << 2) + (lane >> 4);
        float Tr[8];
#pragma unroll
        for (int r = 0; r < 8; ++r)
            Tr[r] = fexp2(trans[((j - r) & 7) * S + j] * LOG2E);
        float al = (j == cc) ? 1.0f : 0.0f;
        int sc = 0;
        int t = tq + 1;
        if (t + 3 <= tm) {
            float c0 = sm[t * 8 + jj];
            float c1 = sm[(t + 1) * 8 + jj];
            float c2 = sm[(t + 2) * 8 + jj];
            float c3 = sm[(t + 3) * 8 + jj];
            pin();
            while (t + 7 <= tm) {
                float d0 = sm[(t + 4) * 8 + jj];
                float d1 = sm[(t + 5) * 8 + jj];
                float d2 = sm[(t + 6) * 8 + jj];
                float d3 = sm[(t + 7) * 8 + jj];
                pin();
                al = denf_step(al, c0, Tr);
                al = denf_step(al, c1, Tr);
                al = denf_step(al, c2, Tr);
                al = denf_step(al, c3, Tr);
                sc += den_renorm(al);
                c0 = d0; c1 = d1; c2 = d2; c3 = d3;
                t += 4;
            }
            al = denf_step(al, c0, Tr);
            al = denf_step(al, c1, Tr);
            al = denf_step(al, c2, Tr);
            al = denf_step(al, c3, Tr);
            sc += den_renorm(al);
            t += 4;
        }
        while (t <= tm) { al = denf_step(al, sm[t * 8 + jj], Tr); ++t; }
        if ((lane & 15) < 8) {
            AST(&MF[cc * 8 + j], al);
            if (j == 0) AST(&MF[64 + cc], __int_as_float(sc));
        }
    } else {
        // =================== DEN MATRIX BWD (R16, proven) ===================
        float* MB = ws + MATB + (size_t)b * 128;
        const int j  = lane & 7;
        const int jj = ((j & 3) << 1) + (j >> 2);
        const int cc = (wv << 2) + (lane >> 4);
        float TrB[8];
#pragma unroll
        for (int r = 0; r < 8; ++r)
            TrB[r] = fexp2(trans[j * S + ((j + r) & 7)] * LOG2E);
        float al = (j == cc) ? 1.0f : 0.0f;
        int sc = 0;
        int t = tq2;
        if (t - 3 >= dlo) {
            float c0 = sm[t * 8 + jj];
            float c1 = sm[(t - 1) * 8 + jj];
            float c2 = sm[(t - 2) * 8 + jj];
            float c3 = sm[(t - 3) * 8 + jj];
            pin();
            while (t - 7 >= dlo) {
                float d0 = sm[(t - 4) * 8 + jj];
                float d1 = sm[(t - 5) * 8 + jj];
                float d2 = sm[(t - 6) * 8 + jj];
                float d3 = sm[(t - 7) * 8 + jj];
                pin();
                al = denb_step(al, c0, TrB);
                al = denb_step(al, c1, TrB);
                al = denb_step(al, c2, TrB);
                al = denb_step(al, c3, TrB);
                sc += den_renorm(al);
                c0 = d0; c1 = d1; c2 = d2; c3 = d3;
                t -= 4;
            }
            al = denb_step(al, c0, TrB);
            al = denb_step(al, c1, TrB);
            al = denb_step(al, c2, TrB);
            al = denb_step(al, c3, TrB);
            sc += den_renorm(al);
            t -= 4;
        }
        while (t >= dlo) { al = denb_step(al, sm[t * 8 + jj], TrB); --t; }
        if ((lane & 15) < 8) {
            AST(&MB[cc * 8 + j], al);
            if (j == 0) AST(&MB[64 + cc], __int_as_float(sc));
        }
    }

    // ---------------- ticket + winner combine (R16, proven) ----------------
    __syncthreads();
    int* wflag = (int*)sm;
    if (tid == 0) {
        __threadfence();
        const int tk = atomicAdd(ticket, 1);
        wflag[0] = (tk == 5 * B - 1) ? 1 : 0;
    }
    __syncthreads();
    if (wflag[0] && tid < 64) {
        __threadfence();
        float acc = 0.0f;
        const int c8 = lane >> 3, j8 = lane & 7;
        for (int bb2 = 0; bb2 < B; ++bb2) {
            const float* nf = ws + 16 + (size_t)bb2 * 640;
            const float* nb = ws + 16 + (size_t)B * 640 + (size_t)bb2 * 640;
            float va = 0.0f, vb = 0.0f;
#pragma unroll
            for (int k = 0; k < 4; ++k)
                va = fmaf(ALD(&nf[lane * 4 + k]), ALD(&nb[lane * 4 + k]), va);
#pragma unroll
            for (int k = 0; k < 4; ++k)
                vb = fmaf(ALD(&nf[256 + lane * 4 + k]),
                          ALD(&nb[256 + lane * 4 + k]), vb);
            const int sa = __float_as_int(ALD(&nf[512 + lane]))
                         + __float_as_int(ALD(&nb[512 + lane]));
            const int sb = __float_as_int(ALD(&nf[576 + lane]))
                         + __float_as_int(ALD(&nb[576 + lane]));
            float pa = (va > 0.0f) ? (flog2(va) + (float)sa) : -3.0e38f;
            float pb = (vb > 0.0f) ? (flog2(vb) + (float)sb) : -3.0e38f;
            float part = lse2(pa, pb);
#pragma unroll
            for (int o = 1; o < 64; o <<= 1)
                part = lse2(part, __shfl_xor(part, o, 64));

            const float* dr = ws + DENR + (size_t)bb2 * 32;
            const float* mf = ws + MATF + (size_t)bb2 * 128;
            const float* mb = ws + MATB + (size_t)bb2 * 128;
            int s1 = __float_as_int(ALD(&mf[64 + c8]));
            int m1 = s1;
#pragma unroll
            for (int o = 8; o < 64; o <<= 1) {
                int oth = __shfl_xor(m1, o, 64);
                m1 = (oth > m1) ? oth : m1;
            }
            int s2 = __float_as_int(ALD(&mb[64 + c8]));
            int m2 = s2;
#pragma unroll
            for (int o = 8; o < 64; o <<= 1) {
                int oth = __shfl_xor(m2, o, 64);
                m2 = (oth > m2) ? oth : m2;
            }
            float t1 = ALD(&dr[c8]) * ALD(&mf[c8 * 8 + j8])
                     * ldexpf(1.0f, s1 - m1);
#pragma unroll
            for (int o = 8; o < 64; o <<= 1) t1 += __shfl_xor(t1, o, 64);
            float t2 = ALD(&dr[16 + c8]) * ALD(&mb[c8 * 8 + j8])
                     * ldexpf(1.0f, s2 - m2);
#pragma unroll
            for (int o = 8; o < 64; o <<= 1) t2 += __shfl_xor(t2, o, 64);
            float pd = t1 * t2;
#pragma unroll
            for (int o = 1; o < 8; o <<= 1) pd += __shfl_xor(pd, o, 64);
            const int scF = __float_as_int(ALD(&dr[8]));
            const int scB = __float_as_int(ALD(&dr[24]));
            float logden = flog2(fmaxf(pd, 1e-37f))
                         + (float)(scF + scB + m1 + m2);
            if (lane == 0) acc += logden - part;
        }
        if (lane == 0) out[0] = acc * (LN2 / (float)B);
    }
}

extern "C" void kernel_launch(void* const* d_in, const int* in_sizes, int n_in,
                              void* d_out, int out_size, void* d_ws, size_t ws_size,
                              hipStream_t stream)
{
    const float* em      = (const float*)d_in[0];
    const float* trans   = (const float*)d_in[1];
    const float* bos     = (const float*)d_in[2];
    const float* eos     = (const float*)d_in[3];
    const int*   lengths = (const int*)d_in[4];
    const int*   targets = (const int*)d_in[5];
    const int*   tlens   = (const int*)d_in[6];
    float* out = (float*)d_out;
    float* ws  = (float*)d_ws;

    const int B  = in_sizes[4];              // 16
    const int SS = in_sizes[1];              // 64
    int S = 1; while (S * S < SS) ++S;       // 8
    const int T = in_sizes[0] / (B * S);     // 2048
    const int L = in_sizes[5] / B;           // 256

    // num blocks: streams 8*(T+2) + 4 ring buffers (4x17x64 float2 = 8704
    // floats) + 4 scale buffers (4x2x64 int = 512). Total ~102.5 KB.
    const size_t shmem = (size_t)(8 * (T + 2) + 8704 + 512) * sizeof(float);

    static bool attr_done = false;
    if (!attr_done) {
        (void)hipFuncSetAttribute((const void*)crf_fused,
                                  hipFuncAttributeMaxDynamicSharedMemorySize,
                                  (int)(112 * 1024));
        attr_done = true;
    }

    (void)hipMemsetAsync(ws, 0, 64, stream); // ticket
    hipLaunchKernelGGL(crf_fused, dim3(5 * B), dim3(128), shmem, stream,
                       em, trans, bos, eos, lengths, targets, tlens,
                       ws, out, B, T, S, L);
}

// Round 10
// 142.210 us; speedup vs baseline: 1.1323x; 1.0065x over previous
//
#include <hip/hip_runtime.h>
#include <math.h>

// CTC-CRF NLL: mean_b( logZ_den(b) - logZ_num(b) ), B=16,T=2048,S=8,L=256.
//
// R21 = R18 (best dispatch: 80.3us, absmax 0) + batched producer ring
// WRITES. Falsified for the ~185cy/step floor: instr count (R13/R15),
// read exposure (R18, partial), barriers (R20), wave-fill (R12),
// composition (R17/R19). Last proven-direction lever: R18's producer
// still issues 19 scattered ds_writes per chunk INSIDE the serial fmaf
// chain (ring slot after every step + renorm rewrites). R21 captures
// post-step states in registers (fwd: E1,X1 -> H[]; bwd: mm0 -> HM[])
// and flushes the ring in 2 contiguous clusters per chunk (after each
// renorm). Values/slots/scales bit-identical to R18; slot 16 (never
// read by fast consumers) skipped; slow paths keep in-step writes
// (producer+consumer always take the same path for a given chunk).
// Den roles (R16 time-split), staging, combine: verbatim R18.

#define LOG2E 1.4426950408889634f
#define LN2   0.69314718055994531f
#define CTL_WSHL1  0x130            // DPP wave_shl:1 (lane63 -> 0)
#define CTL_WSHR1  0x138            // DPP wave_shr:1 (lane0  -> 0)
#define CTL_ROR(r) (0x120 + (r))    // DPP row_ror:r

#define AST(p, v) __hip_atomic_store((p), (v), __ATOMIC_RELAXED, __HIP_MEMORY_SCOPE_AGENT)
#define ALD(p)    __hip_atomic_load((p), __ATOMIC_RELAXED, __HIP_MEMORY_SCOPE_AGENT)

template <int CTRL>
__device__ __forceinline__ float fdpp(float x) {
    return __int_as_float(__builtin_amdgcn_update_dpp(
        0, __float_as_int(x), CTRL, 0xF, 0xF, true));
}
template <int CTRL>
__device__ __forceinline__ int idpp(int x) {
    return __builtin_amdgcn_update_dpp(0, x, CTRL, 0xF, 0xF, true);
}

__device__ __forceinline__ void pin() {
#if __has_builtin(__builtin_amdgcn_sched_barrier)
    __builtin_amdgcn_sched_barrier(0);
#else
    asm volatile("" ::: "memory");
#endif
}

__device__ __forceinline__ float fexp2(float x) {
#if __has_builtin(__builtin_amdgcn_exp2f)
    return __builtin_amdgcn_exp2f(x);
#else
    return exp2f(x);
#endif
}
__device__ __forceinline__ float flog2(float x) {
#if __has_builtin(__builtin_amdgcn_logf)
    return __builtin_amdgcn_logf(x);
#else
    return __log2f(x);
#endif
}
__device__ __forceinline__ float lse2(float a, float b) {   // log2(2^a+2^b)
    float m = fmaxf(a, b);
    float d = fminf(a, b) - m;
    return m + flog2(1.0f + fexp2(d));
}

struct NFC { float tee0, txe0, tee1, txe1, tex0, txx0, tex1, txx1; };
struct NBC { float tex0, txx0, tex1, txx1, teeN0, txeN0, teeN1, txeN1; };

// ================= num fwd: one step (R15/R18 math, verbatim) =============
// WR: write ring slot inside the step (slow path). Fast producer uses
// WR=false and batches the writes outside.
template <bool CONS, bool WR>
__device__ __forceinline__ void nf_step(
    float2 p0, float2 p1, float2 rv, int k,
    float (&E)[2], float (&X)[2], float teeF, float txeF,
    const NFC& c, float2* rEX, int lane)
{
    float nbE = fdpp<CTL_WSHR1>(E[1]);
    float nbX = fdpp<CTL_WSHR1>(X[1]);
    if (CONS && lane == 0) { nbE = rv.x; nbX = rv.y; }
    const float nE0 = p0.x * fmaf(nbE, teeF, nbX * txeF);
    const float nE1 = p1.x * fmaf(E[0], c.tee1, X[0] * c.txe1);
    const float nX0 = p0.y * fmaf(E[0], c.tex0, X[0] * c.txx0);
    const float nX1 = p1.y * fmaf(E[1], c.tex1, X[1] * c.txx1);
    E[0] = nE0; E[1] = nE1; X[0] = nX0; X[1] = nX1;
    if (!CONS && WR) rEX[(k + 1) * 64 + lane] = make_float2(E[1], X[1]);
}

template <bool CONS, bool WR>
__device__ __forceinline__ void nf_renorm(
    float (&E)[2], float (&X)[2], int& s, float& teeF, float& txeF,
    int rsv, int g, int lane, const NFC& c,
    float2* rEX, int* rS, int k, int slot)
{
    float m = fmaxf(fmaxf(E[0], E[1]), fmaxf(X[0], X[1]));
    const bool live = (m > 0.0f);
    const int ex = live ? ((int)(__float_as_uint(m) >> 23) - 126) : 0;
    s += ex;
    int bs = idpp<CTL_WSHR1>(s);
    if (CONS && lane == 0) bs = rsv;
    if (!live) s = bs;
    int d = (g == 0) ? 0 : (bs - s);
    const int extra = (d > 30) ? d : 0;
    s += extra; d -= extra;
    const float fsc = ldexpf(1.0f, -(ex + extra));
    E[0] *= fsc; E[1] *= fsc; X[0] *= fsc; X[1] *= fsc;
    const float fs0 = (g == 0) ? 0.0f : ldexpf(1.0f, d);
    teeF = c.tee0 * fs0; txeF = c.txe0 * fs0;
    if (!CONS && WR) {
        rS[slot * 64 + lane] = s;
        rEX[(k + 1) * 64 + lane] = make_float2(E[1], X[1]);
    }
}

// fast chunk: 16 steps, tb even. Ring reads AND writes batch-clustered.
template <bool CONS>
__device__ __forceinline__ void nf_chunk16(
    const float4* s40, const float4* s41, int tb,
    float (&E)[2], float (&X)[2], int& s, float& teeF, float& txeF,
    const NFC& c, int g, int lane, float2* rEX, int* rS)
{
    const int h = tb >> 1;
    float2 RV[16]; int RS0 = 0, RS1 = 0;
    if (CONS) {
#pragma unroll
        for (int k = 0; k < 16; ++k) RV[k] = rEX[k * 64 + 63];
        RS0 = rS[63]; RS1 = rS[64 + 63];
    } else {
#pragma unroll
        for (int k = 0; k < 16; ++k) RV[k] = make_float2(0.f, 0.f);
    }
    float4 A0[4], A1[4];
#pragma unroll
    for (int j = 0; j < 4; ++j) { A0[j] = s40[h + j]; A1[j] = s41[h + j]; }
    pin();
    float4 B0[4], B1[4];
#pragma unroll
    for (int j = 0; j < 4; ++j) { B0[j] = s40[h + 4 + j]; B1[j] = s41[h + 4 + j]; }
    pin();
    float2 H[9];
    if (!CONS) H[0] = make_float2(E[1], X[1]);        // carry-in (slot 0)
#pragma unroll
    for (int k = 0; k < 8; ++k) {
        const float4 v0 = A0[k >> 1], v1 = A1[k >> 1];
        const float2 p0 = (k & 1) ? make_float2(v0.z, v0.w) : make_float2(v0.x, v0.y);
        const float2 p1 = (k & 1) ? make_float2(v1.z, v1.w) : make_float2(v1.x, v1.y);
        nf_step<CONS, false>(p0, p1, RV[k], k, E, X, teeF, txeF, c, rEX, lane);
        if (!CONS && k < 7) H[k + 1] = make_float2(E[1], X[1]);
    }
    nf_renorm<CONS, false>(E, X, s, teeF, txeF, RS0, g, lane, c, rEX, rS, 7, 0);
    if (!CONS) {
        H[8] = make_float2(E[1], X[1]);               // slot 8 = scaled state
        pin();
#pragma unroll
        for (int k = 0; k < 9; ++k) rEX[k * 64 + lane] = H[k];
        rS[lane] = s;
        pin();
    }
#pragma unroll
    for (int k = 8; k < 16; ++k) {
        const float4 v0 = B0[(k - 8) >> 1], v1 = B1[(k - 8) >> 1];
        const float2 p0 = (k & 1) ? make_float2(v0.z, v0.w) : make_float2(v0.x, v0.y);
        const float2 p1 = (k & 1) ? make_float2(v1.z, v1.w) : make_float2(v1.x, v1.y);
        nf_step<CONS, false>(p0, p1, RV[k], k, E, X, teeF, txeF, c, rEX, lane);
        if (!CONS && k < 15) H[k - 8] = make_float2(E[1], X[1]);
    }
    nf_renorm<CONS, false>(E, X, s, teeF, txeF, RS1, g, lane, c, rEX, rS, 15, 1);
    if (!CONS) {
        // slots 9..15 = states after steps 8..14; slot 16 never read: skip
        pin();
#pragma unroll
        for (int k = 0; k < 7; ++k) rEX[(9 + k) * 64 + lane] = H[k];
        rS[64 + lane] = s;
        pin();
    }
}

// slow chunk: arbitrary n, per-step loads+writes (rare: fwd chunk 0)
template <bool CONS>
__device__ __forceinline__ void nf_chunk_slow(
    const float2* f20, const float2* f21, int tb, int n,
    float (&E)[2], float (&X)[2], int& s, float& teeF, float& txeF,
    const NFC& c, int g, int lane, float2* rEX, int* rS)
{
    if (!CONS) rEX[lane] = make_float2(E[1], X[1]);
    for (int k = 0; k < n; ++k) {
        const float2 p0 = f20[tb + k], p1 = f21[tb + k];
        float2 rv = make_float2(0.f, 0.f);
        if (CONS) rv = rEX[k * 64 + 63];
        nf_step<CONS, true>(p0, p1, rv, k, E, X, teeF, txeF, c, rEX, lane);
        if ((k & 7) == 7) {
            int rsv = 0;
            if (CONS) rsv = rS[(k >> 3) * 64 + 63];
            nf_renorm<CONS, true>(E, X, s, teeF, txeF, rsv, g, lane, c, rEX, rS, k, k >> 3);
        }
    }
}

// ================= num bwd: one step (R15/R18 math, verbatim) =============
// Returns mm0 (the ring value) so the fast producer can batch it.
template <bool CONS, bool WR>
__device__ __forceinline__ float nb_step(
    float2 p0, float2 p1, float rm, int k,
    float (&bE)[2], float (&bX)[2], float teeN1F, float txeN1F,
    const NBC& c, float* rM, int lane)
{
    const float mm0 = p0.x * bE[0];
    const float mm1 = p1.x * bE[1];
    const float m10 = p0.y * bX[0];
    const float m11 = p1.y * bX[1];
    float mup = fdpp<CTL_WSHL1>(mm0);
    if (CONS && lane == 63) mup = rm;
    if (!CONS && WR) rM[k * 64 + lane] = mm0;
    const float nE0 = fmaf(c.tex0, m10, c.teeN0 * mm1);
    const float nX0 = fmaf(c.txx0, m10, c.txeN0 * mm1);
    const float nE1 = fmaf(c.tex1, m11, teeN1F * mup);
    const float nX1 = fmaf(c.txx1, m11, txeN1F * mup);
    bE[0] = nE0; bE[1] = nE1; bX[0] = nX0; bX[1] = nX1;
    return mm0;
}

template <bool CONS, bool WR>
__device__ __forceinline__ void nb_renorm(
    float (&bE)[2], float (&bX)[2], int& s, float& teeN1F, float& txeN1F,
    int rsv, int g, int lane, const NBC& c, int* rS, int slot)
{
    float m = fmaxf(fmaxf(bE[0], bE[1]), fmaxf(bX[0], bX[1]));
    const bool live = (m > 0.0f);
    const int ex = live ? ((int)(__float_as_uint(m) >> 23) - 126) : 0;
    s += ex;
    int bs = idpp<CTL_WSHL1>(s);
    if (CONS && lane == 63) bs = rsv;
    if (!live) s = bs;
    int d = (g == 127) ? 0 : (bs - s);
    const int extra = (d > 30) ? d : 0;
    s += extra; d -= extra;
    const float fsc = ldexpf(1.0f, -(ex + extra));
    bE[0] *= fsc; bE[1] *= fsc; bX[0] *= fsc; bX[1] *= fsc;
    const float fs = (g == 127) ? 0.0f : ldexpf(1.0f, d);
    teeN1F = c.teeN1 * fs; txeN1F = c.txeN1 * fs;
    if (!CONS && WR) rS[slot * 64 + lane] = s;
}

// fast chunk: 16 steps descending from tbh (odd); batched ring I/O
template <bool CONS>
__device__ __forceinline__ void nb_chunk16(
    const float4* s40, const float4* s41, int tbh,
    float (&bE)[2], float (&bX)[2], int& s, float& teeN1F, float& txeN1F,
    const NBC& c, int g, int lane, float* rM, int* rS)
{
    const int h = tbh >> 1;
    float RM[16]; int RS0 = 0, RS1 = 0;
    if (CONS) {
#pragma unroll
        for (int k = 0; k < 16; ++k) RM[k] = rM[k * 64];     // producer lane 0
        RS0 = rS[0]; RS1 = rS[64];                           // producer lane 0
    } else {
#pragma unroll
        for (int k = 0; k < 16; ++k) RM[k] = 0.f;
    }
    float4 A0[4], A1[4];
#pragma unroll
    for (int j = 0; j < 4; ++j) { A0[j] = s40[h - j]; A1[j] = s41[h - j]; }
    pin();
    float4 B0[4], B1[4];
#pragma unroll
    for (int j = 0; j < 4; ++j) { B0[j] = s40[h - 4 - j]; B1[j] = s41[h - 4 - j]; }
    pin();
    float HM[8];
#pragma unroll
    for (int k = 0; k < 8; ++k) {
        const float4 v0 = A0[k >> 1], v1 = A1[k >> 1];
        // t = tbh - k; k even -> t odd -> high half (z,w)
        const float2 p0 = (k & 1) ? make_float2(v0.x, v0.y) : make_float2(v0.z, v0.w);
        const float2 p1 = (k & 1) ? make_float2(v1.x, v1.y) : make_float2(v1.z, v1.w);
        const float mm0 = nb_step<CONS, false>(p0, p1, RM[k], k, bE, bX,
                                               teeN1F, txeN1F, c, rM, lane);
        if (!CONS) HM[k] = mm0;
    }
    nb_renorm<CONS, false>(bE, bX, s, teeN1F, txeN1F, RS0, g, lane, c, rS, 0);
    if (!CONS) {
        pin();
#pragma unroll
        for (int k = 0; k < 8; ++k) rM[k * 64 + lane] = HM[k];
        rS[lane] = s;
        pin();
    }
#pragma unroll
    for (int k = 8; k < 16; ++k) {
        const float4 v0 = B0[(k - 8) >> 1], v1 = B1[(k - 8) >> 1];
        const float2 p0 = (k & 1) ? make_float2(v0.x, v0.y) : make_float2(v0.z, v0.w);
        const float2 p1 = (k & 1) ? make_float2(v1.x, v1.y) : make_float2(v1.z, v1.w);
        const float mm0 = nb_step<CONS, false>(p0, p1, RM[k], k, bE, bX,
                                               teeN1F, txeN1F, c, rM, lane);
        if (!CONS) HM[k - 8] = mm0;
    }
    nb_renorm<CONS, false>(bE, bX, s, teeN1F, txeN1F, RS1, g, lane, c, rS, 1);
    if (!CONS) {
        pin();
#pragma unroll
        for (int k = 0; k < 8; ++k) rM[(8 + k) * 64 + lane] = HM[k];
        rS[64 + lane] = s;
        pin();
    }
}

template <bool CONS>
__device__ __forceinline__ void nb_chunk_slow(
    const float2* f20, const float2* f21, int tbh, int n,
    float (&bE)[2], float (&bX)[2], int& s, float& teeN1F, float& txeN1F,
    const NBC& c, int g, int lane, float* rM, int* rS)
{
    for (int k = 0; k < n; ++k) {
        const float2 p0 = f20[tbh - k], p1 = f21[tbh - k];
        float rm = 0.f;
        if (CONS) rm = rM[k * 64];
        (void)nb_step<CONS, true>(p0, p1, rm, k, bE, bX, teeN1F, txeN1F, c, rM, lane);
        if ((k & 7) == 7) {
            int rsv = 0;
            if (CONS) rsv = rS[(k >> 3) * 64];
            nb_renorm<CONS, true>(bE, bX, s, teeN1F, txeN1F, rsv, g, lane, c, rS, k >> 3);
        }
    }
}

// ---------------- denominator steps (proven) ----------------
__device__ __forceinline__ float denf_step(float al, float emt, const float* Tr) {
    float v1 = fdpp<CTL_ROR(1)>(al);
    float v2 = fdpp<CTL_ROR(2)>(al);
    float v3 = fdpp<CTL_ROR(3)>(al);
    float v4 = fdpp<CTL_ROR(4)>(al);
    float v5 = fdpp<CTL_ROR(5)>(al);
    float v6 = fdpp<CTL_ROR(6)>(al);
    float v7 = fdpp<CTL_ROR(7)>(al);
    float q0 = fmaf(v1, Tr[1], al * Tr[0]);
    float q1 = fmaf(v3, Tr[3], v2 * Tr[2]);
    float q2 = fmaf(v5, Tr[5], v4 * Tr[4]);
    float q3 = fmaf(v7, Tr[7], v6 * Tr[6]);
    return ((q0 + q1) + (q2 + q3)) * emt;
}
__device__ __forceinline__ float denb_step(float al, float emt, const float* TrB) {
    float g  = al * emt;
    float v1 = fdpp<CTL_ROR(7)>(g);
    float v2 = fdpp<CTL_ROR(6)>(g);
    float v3 = fdpp<CTL_ROR(5)>(g);
    float v4 = fdpp<CTL_ROR(4)>(g);
    float v5 = fdpp<CTL_ROR(3)>(g);
    float v6 = fdpp<CTL_ROR(2)>(g);
    float v7 = fdpp<CTL_ROR(1)>(g);
    float q0 = fmaf(v1, TrB[1], g * TrB[0]);
    float q1 = fmaf(v3, TrB[3], v2 * TrB[2]);
    float q2 = fmaf(v5, TrB[5], v4 * TrB[4]);
    float q3 = fmaf(v7, TrB[7], v6 * TrB[6]);
    return (q0 + q1) + (q2 + q3);
}
__device__ __forceinline__ int den_renorm(float& al) {
    float mm = fmaxf(al, fdpp<CTL_ROR(4)>(al));
    mm = fmaxf(mm, fdpp<CTL_ROR(2)>(mm));
    mm = fmaxf(mm, fdpp<CTL_ROR(1)>(mm));
    const int ex = (int)(__float_as_uint(mm) >> 23) - 126;
    al = ldexpf(al, -ex);
    return ex;
}

#define WXP(i, j) fexp2(trans[(i) * S + (j)] * LOG2E)

extern "C" __global__ void __launch_bounds__(128)
crf_fused(const float* __restrict__ em, const float* __restrict__ trans,
          const float* __restrict__ bos, const float* __restrict__ eos,
          const int* __restrict__ lengths, const int* __restrict__ targets,
          const int* __restrict__ tlens,
          float* __restrict__ ws, float* __restrict__ out,
          int B, int T, int S, int L)
{
    extern __shared__ float sm[];
    const int bid  = blockIdx.x;
    const int tid  = threadIdx.x;
    const int lane = tid & 63;
    const int wv   = tid >> 6;
    const int half = S >> 1;                 // = 4
    const int role = bid / B;                // 0 nf, 1 nb, 2 den-real, 3 matF, 4 matB
    const int b    = bid % B;
    const float* gem = em + (size_t)b * T * S;
    const int len = lengths[b];
    const int tm  = (len - 1) >> 1;
    const int P2  = T + 2;                   // padded float2 pitch per stream
    const int RINGF = 8 * P2;                // ring offset (floats)

    float* NF  = ws + 16 + (size_t)b * 640;
    float* NB  = ws + 16 + (size_t)B * 640 + (size_t)b * 640;
    const size_t DENR = 16 + (size_t)(2 * B) * 640;
    const size_t MATF = DENR + (size_t)B * 32;
    const size_t MATB = MATF + (size_t)B * 128;
    int* ticket = (int*)ws;

    // segment boundaries for den split (R16)
    const int tq  = tm >> 1;
    const int dlo = tm + 1, dhi = len - 1;
    const int tq2 = (dhi >= dlo) ? (dlo + ((dhi - dlo) >> 1)) : (dlo - 1);

    // ---------------- staging ----------------
    if (role < 2) {
        float2* s2 = (float2*)sm;
        for (int t = tid; t < T; t += 128) {
            const float4* gr = (const float4*)(gem + t * S);
            float4 a = gr[0], c4 = gr[1];
            s2[0 * P2 + t] = make_float2(fexp2(a.x * LOG2E), fexp2(c4.x * LOG2E));
            s2[1 * P2 + t] = make_float2(fexp2(a.y * LOG2E), fexp2(c4.y * LOG2E));
            s2[2 * P2 + t] = make_float2(fexp2(a.z * LOG2E), fexp2(c4.z * LOG2E));
            s2[3 * P2 + t] = make_float2(fexp2(a.w * LOG2E), fexp2(c4.w * LOG2E));
        }
    } else {
        for (int t = tid; t < T; t += 128) {
            const float4* gr = (const float4*)(gem + t * S);
            float4 a = gr[0], c4 = gr[1];
            float4 w0, w1;
            w0.x = fexp2(a.x * LOG2E); w0.y = fexp2(c4.x * LOG2E);
            w0.z = fexp2(a.y * LOG2E); w0.w = fexp2(c4.y * LOG2E);
            w1.x = fexp2(a.z * LOG2E); w1.y = fexp2(c4.z * LOG2E);
            w1.z = fexp2(a.w * LOG2E); w1.w = fexp2(c4.w * LOG2E);
            ((float4*)sm)[t * 2]     = w0;
            ((float4*)sm)[t * 2 + 1] = w1;
        }
    }
    __syncthreads();

    float2* ringEX = (float2*)(sm + RINGF);       // [2][17][64] float2 (fwd)
    float*  ringM  = sm + RINGF;                  // [2][16][64] float (bwd)
    int*    ringSB = (int*)(sm + RINGF + 4352);   // [2][2][64] int

    if (role == 0) {
        // ===== NUM FWD, preloaded 2-wave pipeline: t = 1..tm =====
        const float2* s2v = (const float2*)sm;
        const int g   = (wv << 6) + lane;
        const int u0 = g * 2;
        const int base = b * L;
        const int e0 = targets[base + ((u0     < L) ? u0     : (L - 1))];
        const int e1 = targets[base + ((u0 + 1 < L) ? u0 + 1 : (L - 1))];
        const int ep = (u0 > 0) ? targets[base + u0 - 1] : e0;
        NFC c;
        c.tee0 = WXP(ep, e0);          c.txe0 = WXP(ep + half, e0);
        c.tee1 = WXP(e0, e1);          c.txe1 = WXP(e0 + half, e1);
        c.tex0 = WXP(e0, e0 + half);   c.txx0 = WXP(e0 + half, e0 + half);
        c.tex1 = WXP(e1, e1 + half);   c.txx1 = WXP(e1 + half, e1 + half);
        const float2* f20 = s2v + e0 * P2;
        const float2* f21 = s2v + e1 * P2;
        const float4* s40 = (const float4*)f20;
        const float4* s41 = (const float4*)f21;
        float E[2] = {0.f, 0.f}, X[2] = {0.f, 0.f};
        int s = 0;
        if (g == 0) E[0] = fexp2(bos[e0] * LOG2E) * f20[0].x;
        float teeF = (g == 0) ? 0.0f : c.tee0;
        float txeF = (g == 0) ? 0.0f : c.txe0;

        const int NCH = (tm >= 1) ? ((tm >> 4) + 1) : 0;
        for (int ph = 0; ph <= NCH; ++ph) {
            const int ci = (wv == 0) ? ph : ph - 1;   // producer = wave0
            if (ci >= 0 && ci < NCH) {
                const int tb = ci ? (ci << 4) : 1;
                int te = (ci << 4) + 15; if (te > tm) te = tm;
                const int n = te - tb + 1;
                float2* rEX = ringEX + (ci & 1) * (17 * 64);
                int*    rS  = ringSB + (ci & 1) * 128;
                if (n == 16 && !(tb & 1)) {
                    if (wv == 0)
                        nf_chunk16<false>(s40, s41, tb, E, X, s, teeF, txeF,
                                          c, g, lane, rEX, rS);
                    else
                        nf_chunk16<true>(s40, s41, tb, E, X, s, teeF, txeF,
                                         c, g, lane, rEX, rS);
                } else {
                    if (wv == 0)
                        nf_chunk_slow<false>(f20, f21, tb, n, E, X, s, teeF, txeF,
                                             c, g, lane, rEX, rS);
                    else
                        nf_chunk_slow<true>(f20, f21, tb, n, E, X, s, teeF, txeF,
                                            c, g, lane, rEX, rS);
                }
            }
            __syncthreads();
        }
        AST(&NF[g * 4 + 0], E[0]);
        AST(&NF[g * 4 + 1], E[1]);
        AST(&NF[g * 4 + 2], X[0]);
        AST(&NF[g * 4 + 3], X[1]);
        AST(&NF[512 + g], __int_as_float(s));
    } else if (role == 1) {
        // ===== NUM BWD, preloaded 2-wave pipeline: t = len-1..tm+1 =====
        const float2* s2v = (const float2*)sm;
        const int g   = (wv << 6) + lane;
        const int u0 = g * 2;
        const int base = b * L;
        const int e0 = targets[base + ((u0     < L) ? u0     : (L - 1))];
        const int e1 = targets[base + ((u0 + 1 < L) ? u0 + 1 : (L - 1))];
        const int e2 = targets[base + ((u0 + 2 < L) ? u0 + 2 : (L - 1))];
        NBC c;
        c.tex0 = WXP(e0, e0 + half);  c.txx0 = WXP(e0 + half, e0 + half);
        c.tex1 = WXP(e1, e1 + half);  c.txx1 = WXP(e1 + half, e1 + half);
        c.teeN0 = WXP(e0, e1);        c.txeN0 = WXP(e0 + half, e1);
        c.teeN1 = WXP(e1, e2);        c.txeN1 = WXP(e1 + half, e2);
        if (g == 127) { c.teeN1 = 0.0f; c.txeN1 = 0.0f; }
        const float2* f20 = s2v + e0 * P2;
        const float2* f21 = s2v + e1 * P2;
        const float4* s40 = (const float4*)f20;
        const float4* s41 = (const float4*)f21;
        float bE[2] = {0.f, 0.f}, bX[2] = {0.f, 0.f};
        const int uf = tlens[b] - 1;
        if (g == (uf >> 1)) {
            const int kf = uf & 1;
            const int ef = kf ? e1 : e0;
            bE[kf] = fexp2(eos[ef] * LOG2E);
            bX[kf] = fexp2(eos[ef + half] * LOG2E);
        }
        int s = 0;
        float teeN1F = c.teeN1, txeN1F = c.txeN1;

        const int th = len - 1, tlo = tm + 1;
        const int nbs = th - tlo + 1;
        const int NCH = (nbs > 0) ? ((nbs + 15) >> 4) : 0;
        for (int ph = 0; ph <= NCH; ++ph) {
            const int ci = (wv == 1) ? ph : ph - 1;   // producer = wave1
            if (ci >= 0 && ci < NCH) {
                const int tbh = th - (ci << 4);
                int tbl = tbh - 15; if (tbl < tlo) tbl = tlo;
                const int n = tbh - tbl + 1;
                float* rM = ringM + (ci & 1) * 1024;
                int*   rS = ringSB + (ci & 1) * 128;
                if (n == 16 && (tbh & 1)) {
                    if (wv == 1)
                        nb_chunk16<false>(s40, s41, tbh, bE, bX, s, teeN1F, txeN1F,
                                          c, g, lane, rM, rS);
                    else
                        nb_chunk16<true>(s40, s41, tbh, bE, bX, s, teeN1F, txeN1F,
                                         c, g, lane, rM, rS);
                } else {
                    if (wv == 1)
                        nb_chunk_slow<false>(f20, f21, tbh, n, bE, bX, s, teeN1F, txeN1F,
                                             c, g, lane, rM, rS);
                    else
                        nb_chunk_slow<true>(f20, f21, tbh, n, bE, bX, s, teeN1F, txeN1F,
                                            c, g, lane, rM, rS);
                }
            }
            __syncthreads();
        }
        AST(&NB[g * 4 + 0], bE[0]);
        AST(&NB[g * 4 + 1], bE[1]);
        AST(&NB[g * 4 + 2], bX[0]);
        AST(&NB[g * 4 + 3], bX[1]);
        AST(&NB[512 + g], __int_as_float(s));
    } else if (role == 2) {
        // =================== DEN REAL (R16, proven) ===================
        float* DR = ws + DENR + (size_t)b * 32;
        const int j  = lane & 7;
        const int jj = ((j & 3) << 1) + (j >> 2);
        if (wv == 0) {
            float Tr[8];
#pragma unroll
            for (int r = 0; r < 8; ++r)
                Tr[r] = fexp2(trans[((j - r) & 7) * S + j] * LOG2E);
            float al = fexp2(bos[j] * LOG2E) * sm[jj];
            int sc = 0;
            int t = 1;
            if (t + 3 <= tq) {
                float c0 = sm[t * 8 + jj];
                float c1 = sm[(t + 1) * 8 + jj];
                float c2 = sm[(t + 2) * 8 + jj];
                float c3 = sm[(t + 3) * 8 + jj];
                pin();
                while (t + 7 <= tq) {
                    float d0 = sm[(t + 4) * 8 + jj];
                    float d1 = sm[(t + 5) * 8 + jj];
                    float d2 = sm[(t + 6) * 8 + jj];
                    float d3 = sm[(t + 7) * 8 + jj];
                    pin();
                    al = denf_step(al, c0, Tr);
                    al = denf_step(al, c1, Tr);
                    al = denf_step(al, c2, Tr);
                    al = denf_step(al, c3, Tr);
                    sc += den_renorm(al);
                    c0 = d0; c1 = d1; c2 = d2; c3 = d3;
                    t += 4;
                }
                al = denf_step(al, c0, Tr);
                al = denf_step(al, c1, Tr);
                al = denf_step(al, c2, Tr);
                al = denf_step(al, c3, Tr);
                sc += den_renorm(al);
                t += 4;
            }
            while (t <= tq) { al = denf_step(al, sm[t * 8 + jj], Tr); ++t; }
            if (lane < 8) {
                AST(&DR[j], al);
                if (j == 0) AST(&DR[8], __int_as_float(sc));
            }
        } else {
            float TrB[8];
#pragma unroll
            for (int r = 0; r < 8; ++r)
                TrB[r] = fexp2(trans[j * S + ((j + r) & 7)] * LOG2E);
            float al = fexp2(eos[j] * LOG2E);
            int sc = 0;
            int t = dhi;
            const int tloR = tq2 + 1;
            if (t - 3 >= tloR) {
                float c0 = sm[t * 8 + jj];
                float c1 = sm[(t - 1) * 8 + jj];
                float c2 = sm[(t - 2) * 8 + jj];
                float c3 = sm[(t - 3) * 8 + jj];
                pin();
                while (t - 7 >= tloR) {
                    float d0 = sm[(t - 4) * 8 + jj];
                    float d1 = sm[(t - 5) * 8 + jj];
                    float d2 = sm[(t - 6) * 8 + jj];
                    float d3 = sm[(t - 7) * 8 + jj];
                    pin();
                    al = denb_step(al, c0, TrB);
                    al = denb_step(al, c1, TrB);
                    al = denb_step(al, c2, TrB);
                    al = denb_step(al, c3, TrB);
                    sc += den_renorm(al);
                    c0 = d0; c1 = d1; c2 = d2; c3 = d3;
                    t -= 4;
                }
                al = denb_step(al, c0, TrB);
                al = denb_step(al, c1, TrB);
                al = denb_step(al, c2, TrB);
                al = denb_step(al, c3, TrB);
                sc += den_renorm(al);
                t -= 4;
            }
            while (t >= tloR) { al = denb_step(al, sm[t * 8 + jj], TrB); --t; }
            if (lane < 8) {
                AST(&DR[16 + j], al);
                if (j == 0) AST(&DR[24], __int_as_float(sc));
            }
        }
    } else if (role == 3) {
        // =================== DEN MATRIX FWD (R16, proven) ===================
        float* MF = ws + MATF + (size_t)b * 128;
        const int j  = lane & 7;
        const int jj = ((j & 3) << 1) + (j >> 2);
        const int cc = (wv << 2) + (lane >> 4);
        float Tr[8];
#pragma unroll
        for (int r = 0; r < 8; ++r)
            Tr[r] = fexp2(trans[((j - r) & 7) * S + j] * LOG2E);
        float al = (j == cc) ? 1.0f : 0.0f;
        int sc = 0;
        int t = tq + 1;
        if (t + 3 <= tm) {
            float c0 = sm[t * 8 + jj];
            float c1 = sm[(t + 1) * 8 + jj];
            float c2 = sm[(t + 2) * 8 + jj];
            float c3 = sm[(t + 3) * 8 + jj];
            pin();
            while (t + 7 <= tm) {
                float d0 = sm[(t + 4) * 8 + jj];
                float d1 = sm[(t + 5) * 8 + jj];
                float d2 = sm[(t + 6) * 8 + jj];
                float d3 = sm[(t + 7) * 8 + jj];
                pin();
                al = denf_step(al, c0, Tr);
                al = denf_step(al, c1, Tr);
                al = denf_step(al, c2, Tr);
                al = denf_step(al, c3, Tr);
                sc += den_renorm(al);
                c0 = d0; c1 = d1; c2 = d2; c3 = d3;
                t += 4;
            }
            al = denf_step(al, c0, Tr);
            al = denf_step(al, c1, Tr);
            al = denf_step(al, c2, Tr);
            al = denf_step(al, c3, Tr);
            sc += den_renorm(al);
            t += 4;
        }
        while (t <= tm) { al = denf_step(al, sm[t * 8 + jj], Tr); ++t; }
        if ((lane & 15) < 8) {
            AST(&MF[cc * 8 + j], al);
            if (j == 0) AST(&MF[64 + cc], __int_as_float(sc));
        }
    } else {
        // =================== DEN MATRIX BWD (R16, proven) ===================
        float* MB = ws + MATB + (size_t)b * 128;
        const int j  = lane & 7;
        const int jj = ((j & 3) << 1) + (j >> 2);
        const int cc = (wv << 2) + (lane >> 4);
        float TrB[8];
#pragma unroll
        for (int r = 0; r < 8; ++r)
            TrB[r] = fexp2(trans[j * S + ((j + r) & 7)] * LOG2E);
        float al = (j == cc) ? 1.0f : 0.0f;
        int sc = 0;
        int t = tq2;
        if (t - 3 >= dlo) {
            float c0 = sm[t * 8 + jj];
            float c1 = sm[(t - 1) * 8 + jj];
            float c2 = sm[(t - 2) * 8 + jj];
            float c3 = sm[(t - 3) * 8 + jj];
            pin();
            while (t - 7 >= dlo) {
                float d0 = sm[(t - 4) * 8 + jj];
                float d1 = sm[(t - 5) * 8 + jj];
                float d2 = sm[(t - 6) * 8 + jj];
                float d3 = sm[(t - 7) * 8 + jj];
                pin();
                al = denb_step(al, c0, TrB);
                al = denb_step(al, c1, TrB);
                al = denb_step(al, c2, TrB);
                al = denb_step(al, c3, TrB);
                sc += den_renorm(al);
                c0 = d0; c1 = d1; c2 = d2; c3 = d3;
                t -= 4;
            }
            al = denb_step(al, c0, TrB);
            al = denb_step(al, c1, TrB);
            al = denb_step(al, c2, TrB);
            al = denb_step(al, c3, TrB);
            sc += den_renorm(al);
            t -= 4;
        }
        while (t >= dlo) { al = denb_step(al, sm[t * 8 + jj], TrB); --t; }
        if ((lane & 15) < 8) {
            AST(&MB[cc * 8 + j], al);
            if (j == 0) AST(&MB[64 + cc], __int_as_float(sc));
        }
    }

    // ---------------- ticket + winner combine (R16, proven) ----------------
    __syncthreads();
    int* wflag = (int*)sm;
    if (tid == 0) {
        __threadfence();
        const int tk = atomicAdd(ticket, 1);
        wflag[0] = (tk == 5 * B - 1) ? 1 : 0;
    }
    __syncthreads();
    if (wflag[0] && tid < 64) {
        __threadfence();
        float acc = 0.0f;
        const int c8 = lane >> 3, j8 = lane & 7;
        for (int bb2 = 0; bb2 < B; ++bb2) {
            const float* nf = ws + 16 + (size_t)bb2 * 640;
            const float* nb = ws + 16 + (size_t)B * 640 + (size_t)bb2 * 640;
            float va = 0.0f, vb = 0.0f;
#pragma unroll
            for (int k = 0; k < 4; ++k)
                va = fmaf(ALD(&nf[lane * 4 + k]), ALD(&nb[lane * 4 + k]), va);
#pragma unroll
            for (int k = 0; k < 4; ++k)
                vb = fmaf(ALD(&nf[256 + lane * 4 + k]),
                          ALD(&nb[256 + lane * 4 + k]), vb);
            const int sa = __float_as_int(ALD(&nf[512 + lane]))
                         + __float_as_int(ALD(&nb[512 + lane]));
            const int sb = __float_as_int(ALD(&nf[576 + lane]))
                         + __float_as_int(ALD(&nb[576 + lane]));
            float pa = (va > 0.0f) ? (flog2(va) + (float)sa) : -3.0e38f;
            float pb = (vb > 0.0f) ? (flog2(vb) + (float)sb) : -3.0e38f;
            float part = lse2(pa, pb);
#pragma unroll
            for (int o = 1; o < 64; o <<= 1)
                part = lse2(part, __shfl_xor(part, o, 64));

            const float* dr = ws + DENR + (size_t)bb2 * 32;
            const float* mf = ws + MATF + (size_t)bb2 * 128;
            const float* mb = ws + MATB + (size_t)bb2 * 128;
            int s1 = __float_as_int(ALD(&mf[64 + c8]));
            int m1 = s1;
#pragma unroll
            for (int o = 8; o < 64; o <<= 1) {
                int oth = __shfl_xor(m1, o, 64);
                m1 = (oth > m1) ? oth : m1;
            }
            int s2 = __float_as_int(ALD(&mb[64 + c8]));
            int m2 = s2;
#pragma unroll
            for (int o = 8; o < 64; o <<= 1) {
                int oth = __shfl_xor(m2, o, 64);
                m2 = (oth > m2) ? oth : m2;
            }
            float t1 = ALD(&dr[c8]) * ALD(&mf[c8 * 8 + j8])
                     * ldexpf(1.0f, s1 - m1);
#pragma unroll
            for (int o = 8; o < 64; o <<= 1) t1 += __shfl_xor(t1, o, 64);
            float t2 = ALD(&dr[16 + c8]) * ALD(&mb[c8 * 8 + j8])
                     * ldexpf(1.0f, s2 - m2);
#pragma unroll
            for (int o = 8; o < 64; o <<= 1) t2 += __shfl_xor(t2, o, 64);
            float pd = t1 * t2;
#pragma unroll
            for (int o = 1; o < 8; o <<= 1) pd += __shfl_xor(pd, o, 64);
            const int scF = __float_as_int(ALD(&dr[8]));
            const int scB = __float_as_int(ALD(&dr[24]));
            float logden = flog2(fmaxf(pd, 1e-37f))
                         + (float)(scF + scB + m1 + m2);
            if (lane == 0) acc += logden - part;
        }
        if (lane == 0) out[0] = acc * (LN2 / (float)B);
    }
}

extern "C" void kernel_launch(void* const* d_in, const int* in_sizes, int n_in,
                              void* d_out, int out_size, void* d_ws, size_t ws_size,
                              hipStream_t stream)
{
    const float* em      = (const float*)d_in[0];
    const float* trans   = (const float*)d_in[1];
    const float* bos     = (const float*)d_in[2];
    const float* eos     = (const float*)d_in[3];
    const int*   lengths = (const int*)d_in[4];
    const int*   targets = (const int*)d_in[5];
    const int*   tlens   = (const int*)d_in[6];
    float* out = (float*)d_out;
    float* ws  = (float*)d_ws;

    const int B  = in_sizes[4];              // 16
    const int SS = in_sizes[1];              // 64
    int S = 1; while (S * S < SS) ++S;       // 8
    const int T = in_sizes[0] / (B * S);     // 2048
    const int L = in_sizes[5] / B;           // 256

    // num blocks: streams 8*(T+2) + ring (4352 floats) + ringS (256 ints)
    const size_t shmem = (size_t)(8 * (T + 2) + 4352 + 256) * sizeof(float);

    static bool attr_done = false;
    if (!attr_done) {
        (void)hipFuncSetAttribute((const void*)crf_fused,
                                  hipFuncAttributeMaxDynamicSharedMemorySize,
                                  (int)(96 * 1024));
        attr_done = true;
    }

    (void)hipMemsetAsync(ws, 0, 64, stream); // ticket
    hipLaunchKernelGGL(crf_fused, dim3(5 * B), dim3(128), shmem, stream,
                       em, trans, bos, eos, lengths, targets, tlens,
                       ws, out, B, T, S, L);
}